// Round 2
// baseline (231111.523 us; speedup 1.0000x reference)
//
#include <hip/hip_runtime.h>
#include <hip/hip_bf16.h>

typedef unsigned short u16;
typedef unsigned int   u32;

#define NTHR 256
#define NBLK 512      // persistent grid: 2 blocks/CU * 256 CUs guaranteed resident

#define BATCH 32
#define TENC  200
#define NMELS 80
#define TMELS 800
#define NSTEP 400

// ---- ws float offsets (after 256B reserved region; barrier ints live in the reserved region) ----
#define OFF_AH    0          // 2 * 32*1024 double buffered: ah(s) lives at (s&1)
#define OFF_ACS   65536
#define OFF_DH    98304
#define OFF_DCS   131072
#define OFF_CTX   163840     // 2 * 32*512 double buffered: ctx(s) lives at (s&1)
#define OFF_AW    196608     // 32*200
#define OFF_FBUF  203008     // 32*200*8
#define OFF_PBUF  254208     // 32*200
#define OFF_GPART 260608     // 4096*32 ([row*32+b])
#define OFF_X     391680     // 400*32*256
#define FLOAT_END 3668480    // OFF_X + 3276800
#define ZERO_CNT  196608     // zero [0, OFF_AW)

// ---- bf16 region offsets (u16 indices, base = ws + FLOAT_END) ----
#define B_AWIH 0            // 4096*768
#define B_AWHH 3145728      // 4096*1024
#define B_DWIH 7340032      // 4096*1536
#define B_DWHH 13631488     // 4096*1024
#define B_ACW  17825792     // 160*1536
#define B_WQ   18071552     // 128*1024
#define B_MEMT 18202624     // 32*512*200  [b][d][t]

struct KArgs {
  const float *mels, *memory, *pW1, *pb1, *pW2, *pb2;
  const float *aWih, *aWhh, *abih, *abhh;
  const float *Wq, *bq, *V, *F, *U, *T, *Tb, *vv, *prior;
  const float *dWih, *dWhh, *dbih, *dbhh, *acW, *acb;
  float *out;
  float *ws;
  u16   *wb;
  int   *bar;
};

__device__ __forceinline__ float sigf(float x) {
  x = fminf(fmaxf(x, -30.f), 30.f);
  return 1.0f / (1.0f + __expf(-x));
}
__device__ __forceinline__ float ftanh(float x) {
  x = fminf(fmaxf(x, -15.f), 15.f);
  float e = __expf(2.f * x);
  return (e - 1.f) / (e + 1.f);
}
__device__ __forceinline__ float blo(u32 u) {
  union { u32 i; float f; } v; v.i = u << 16; return v.f;
}
__device__ __forceinline__ float bhi(u32 u) {
  union { u32 i; float f; } v; v.i = u & 0xffff0000u; return v.f;
}
__device__ __forceinline__ u16 f2b(float x) {
  __hip_bfloat16 h = __float2bfloat16(x);
  return *reinterpret_cast<u16*>(&h);
}

// ---- software grid barrier (sense via monotonically increasing generation) ----
// bar[0] = arrival counter, bar[1] = generation. Device-scope atomics chain a
// release (fetch_add on cnt) -> release store (gen) -> acquire load (gen),
// making all pre-barrier global writes visible to all post-barrier readers
// across XCDs. Spin is capped: on timeout we bail (wrong answer, not a hang).
__device__ __forceinline__ void gbar(int* bar, bool& bailed) {
  __syncthreads();
  if (threadIdx.x == 0 && !bailed) {
    __threadfence();
    int g = __hip_atomic_load(&bar[1], __ATOMIC_RELAXED, __HIP_MEMORY_SCOPE_AGENT);
    int a = __hip_atomic_fetch_add(&bar[0], 1, __ATOMIC_ACQ_REL, __HIP_MEMORY_SCOPE_AGENT);
    if (a == NBLK - 1) {
      __hip_atomic_store(&bar[0], 0, __ATOMIC_RELAXED, __HIP_MEMORY_SCOPE_AGENT);
      __hip_atomic_store(&bar[1], g + 1, __ATOMIC_RELEASE, __HIP_MEMORY_SCOPE_AGENT);
    } else {
      int it = 0;
      while (__hip_atomic_load(&bar[1], __ATOMIC_ACQUIRE, __HIP_MEMORY_SCOPE_AGENT) == g) {
        __builtin_amdgcn_s_sleep(1);
        if (++it > (1 << 25)) { bailed = true; break; }
      }
    }
    __threadfence();
  }
  __syncthreads();
}

// direct activation load: 32 consecutive floats (16B-aligned)
__device__ __forceinline__ void loadx(const float* src, float* xin) {
  const float4* p = (const float4*)src;
  #pragma unroll
  for (int q = 0; q < 8; ++q) {
    float4 v = p[q];
    xin[q*4+0] = v.x; xin[q*4+1] = v.y; xin[q*4+2] = v.z; xin[q*4+3] = v.w;
  }
}

// 32-K dot with bf16 weight row-chunk (4 uint4 = 32 bf16)
__device__ __forceinline__ float dot32b(const float* xin, const u16* w) {
  const uint4* wp = (const uint4*)w;
  float acc = 0.f;
  #pragma unroll
  for (int q = 0; q < 4; ++q) {
    uint4 wv = wp[q];
    acc += blo(wv.x)*xin[q*8+0] + bhi(wv.x)*xin[q*8+1]
         + blo(wv.y)*xin[q*8+2] + bhi(wv.y)*xin[q*8+3]
         + blo(wv.z)*xin[q*8+4] + bhi(wv.z)*xin[q*8+5]
         + blo(wv.w)*xin[q*8+6] + bhi(wv.w)*xin[q*8+7];
  }
  return acc;
}

// per-(b,seg) acc[8] -> per-(r=t>>5, b=t&31) total; smred: 2048 floats
__device__ __forceinline__ float reduce8(float* smred, const float* acc) {
  const int t = threadIdx.x;
  const int b = t & 31, seg = t >> 5;
  __syncthreads();
  #pragma unroll
  for (int r = 0; r < 8; ++r) smred[(seg*8 + r)*32 + b] = acc[r];
  __syncthreads();
  const int r2 = t >> 5, b2 = t & 31;
  float tot = 0.f;
  #pragma unroll
  for (int sgi = 0; sgi < 8; ++sgi) tot += smred[(sgi*8 + r2)*32 + b2];
  return tot;
}

// output projection for step sprev (8 rows per job), bf16 acW
__device__ __forceinline__ void outproj(const KArgs& a, float* smred,
                                        const float* dh, const float* ctx,
                                        int pb, int sprev) {
  const int tid = threadIdx.x;
  const int b = tid & 31, seg = tid >> 5;
  const u16* wb = a.wb;
  float acc[8];
  #pragma unroll
  for (int r = 0; r < 8; ++r) acc[r] = 0.f;
  #pragma unroll 2
  for (int kc = 0; kc < 6; ++kc) {
    const float* src = (kc < 4) ? (dh + b*1024 + kc*256) : (ctx + b*512 + (kc-4)*256);
    float xin[32];
    loadx(src + seg*32, xin);
    #pragma unroll
    for (int r = 0; r < 8; ++r) {
      const int rr = pb*8 + r;
      acc[r] += dot32b(xin, wb + B_ACW + rr*1536 + kc*256 + seg*32);
    }
  }
  float tot = reduce8(smred, acc);
  const int r2 = tid >> 5, b2 = tid & 31;
  const int rr = pb*8 + r2;
  tot += a.acb[rr];
  a.out[(b2*NMELS + (rr >> 1))*TMELS + sprev*2 + (rr & 1)] = tot;
}

// ======== DCA (one block per batch) ========
__device__ __forceinline__ void dca_step(const KArgs& a, float* sm, int b, int s,
                                         const float* ah_new, float* aw,
                                         const float* fbuf, const float* pbuf, float* ctx) {
  const int tid = threadIdx.x;
  const u16* wb = a.wb;
  float* s_ah  = sm;            // 1024
  float* s_awp = sm + 1024;     // 224 (padded aw_prev)
  float* s_q   = sm + 1248;     // 128
  float* s_G   = sm + 1376;     // 176
  float* s_e   = sm + 1552;     // 208
  float* s_gg  = sm + 1760;     // 1600 [pos*8+d]
  float* s_ff  = sm + 3360;     // 1600 [pos*8+j]
  float* s_red = sm + 4960;     // 256
  float* s_awn = sm + 5216;     // 200
  for (int i = tid; i < 1024; i += NTHR) s_ah[i] = ah_new[b*1024 + i];
  if (tid < 220) s_awp[tid] = (tid >= 10 && tid < 210) ? aw[b*TENC + tid - 10] : 0.f;
  for (int i = tid; i < 1600; i += NTHR) s_ff[i] = fbuf[b*1600 + i];
  __syncthreads();
  // q = tanh(Wq @ ah + bq), bf16 Wq, split K across 2 halves
  {
    const int o = tid & 127, half = tid >> 7;
    const uint4* wq = (const uint4*)(wb + B_WQ + o*1024 + half*512);
    const float* xa = s_ah + half*512;
    float p = 0.f;
    #pragma unroll 8
    for (int q8 = 0; q8 < 64; ++q8) {
      uint4 w = wq[q8];
      const float* xq = xa + q8*8;
      p += blo(w.x)*xq[0] + bhi(w.x)*xq[1] + blo(w.y)*xq[2] + bhi(w.y)*xq[3]
         + blo(w.z)*xq[4] + bhi(w.z)*xq[5] + blo(w.w)*xq[6] + bhi(w.w)*xq[7];
    }
    s_red[tid] = p;
  }
  __syncthreads();
  if (tid < 128) s_q[tid] = ftanh(s_red[tid] + s_red[128 + tid] + a.bq[tid]);
  __syncthreads();
  // G = q @ V^T  (168 outputs, fp32 V)
  if (tid < 168) {
    const float4* vp = (const float4*)(a.V + tid*128);
    float p = 0.f;
    #pragma unroll
    for (int q4 = 0; q4 < 32; ++q4) {
      float4 w = vp[q4];
      const float* xq = s_q + q4*4;
      p += w.x*xq[0] + w.y*xq[1] + w.z*xq[2] + w.w*xq[3];
    }
    s_G[tid] = p;
  }
  __syncthreads();
  // dynamic conv: g[pos][d]
  for (int idx = tid; idx < 1600; idx += NTHR) {
    const int pos = idx >> 3, d = idx & 7;
    float p = 0.f;
    #pragma unroll
    for (int tau = 0; tau < 21; ++tau) p += s_awp[pos + tau] * s_G[d*21 + tau];
    s_gg[idx] = p;
  }
  __syncthreads();
  // energies: e[pos] = v . tanh(U f + T g + Tb) + p[pos]
  #pragma unroll 1
  for (int ro = 0; ro < 4; ++ro) {
    const int pos = ro*64 + (tid >> 2), sub = tid & 3;
    float av = 0.f;
    if (pos < 200) {
      const float* fpos = s_ff + pos*8;
      const float* gpos = s_gg + pos*8;
      #pragma unroll 4
      for (int fi = 0; fi < 32; ++fi) {
        const int ff = sub*32 + fi;
        const float4* Up = (const float4*)(a.U + ff*8);
        const float4* Tp = (const float4*)(a.T + ff*8);
        float4 u0 = Up[0], u1 = Up[1], t0 = Tp[0], t1 = Tp[1];
        float h = a.Tb[ff];
        h += u0.x*fpos[0] + u0.y*fpos[1] + u0.z*fpos[2] + u0.w*fpos[3]
           + u1.x*fpos[4] + u1.y*fpos[5] + u1.z*fpos[6] + u1.w*fpos[7];
        h += t0.x*gpos[0] + t0.y*gpos[1] + t0.z*gpos[2] + t0.w*gpos[3]
           + t1.x*gpos[4] + t1.y*gpos[5] + t1.z*gpos[6] + t1.w*gpos[7];
        av += a.vv[ff] * ftanh(h);
      }
    }
    av += __shfl_xor(av, 1);
    av += __shfl_xor(av, 2);
    if (sub == 0 && pos < 200) s_e[pos] = av + pbuf[b*TENC + pos];
  }
  __syncthreads();
  // softmax over 200
  float mval = (tid < 200) ? s_e[tid] : -1e30f;
  #pragma unroll
  for (int off = 32; off > 0; off >>= 1) mval = fmaxf(mval, __shfl_xor(mval, off));
  if ((tid & 63) == 0) s_red[tid >> 6] = mval;
  __syncthreads();
  const float m = fmaxf(fmaxf(s_red[0], s_red[1]), fmaxf(s_red[2], s_red[3]));
  const float ex = (tid < 200) ? __expf(s_e[tid] - m) : 0.f;
  float sv = ex;
  #pragma unroll
  for (int off = 32; off > 0; off >>= 1) sv += __shfl_xor(sv, off);
  if ((tid & 63) == 0) s_red[4 + (tid >> 6)] = sv;
  __syncthreads();
  const float inv = 1.f / (s_red[4] + s_red[5] + s_red[6] + s_red[7]);
  if (tid < 200) {
    const float awv = ex * inv;
    aw[b*TENC + tid] = awv;
    s_awn[tid] = awv;
    a.out[2048000 + b*80000 + tid*400 + s] = awv;
  }
  __syncthreads();
  // ctx = aw_new @ memory[b]   (bf16 memT [b][d][t], sequential uint4)
  #pragma unroll 1
  for (int d = tid; d < 512; d += NTHR) {
    const uint4* mp = (const uint4*)(wb + B_MEMT + b*102400 + d*200);
    float p = 0.f;
    #pragma unroll 5
    for (int q = 0; q < 25; ++q) {
      uint4 v = mp[q];
      const float* aa = s_awn + q*8;
      p += blo(v.x)*aa[0] + bhi(v.x)*aa[1] + blo(v.y)*aa[2] + bhi(v.y)*aa[3]
         + blo(v.z)*aa[4] + bhi(v.z)*aa[5] + blo(v.w)*aa[6] + bhi(v.w)*aa[7];
    }
    ctx[b*512 + d] = p;
  }
}

// ======== J1: attn LSTM for step s (u0 = 2*job, 2 units) ========
// reads ctx(s-1) = ctxbuf[(s+1)&1], ah(s-1) = ahbuf[(s+1)&1], X(s); writes ah(s) = ahbuf[s&1], acs
__device__ __forceinline__ void j1_job(const KArgs& a, float* sm, int s, int u0) {
  float* smred = sm;
  float* smg   = sm + 2048;
  const int tid = threadIdx.x;
  float* ws = a.ws;
  const u16* wb = a.wb;
  float* ah_prev = ws + OFF_AH + (((s + 1) & 1) * 32768);
  float* ah_new  = ws + OFF_AH + (((s) & 1) * 32768);
  float* acs = ws + OFF_ACS;
  const float* ctxp = ws + OFF_CTX + (((s + 1) & 1) * 16384);
  const float* Xs = ws + OFF_X + s * BATCH * 256;
  const int b = tid & 31, seg = tid >> 5;
  float acc[8];
  #pragma unroll
  for (int r = 0; r < 8; ++r) acc[r] = 0.f;
  #pragma unroll 2
  for (int kc = 0; kc < 7; ++kc) {
    const float* src = (kc < 2)  ? (ctxp + b*512 + kc*256)
                     : (kc == 2) ? (Xs + b*256)
                                 : (ah_prev + b*1024 + (kc-3)*256);
    float xin[32];
    loadx(src + seg*32, xin);
    #pragma unroll
    for (int r = 0; r < 8; ++r) {
      const int rr = (r>>1)*1024 + u0 + (r&1);
      const u16* wr = (kc < 3) ? (wb + B_AWIH + rr*768 + kc*256 + seg*32)
                               : (wb + B_AWHH + rr*1024 + (kc-3)*256 + seg*32);
      acc[r] += dot32b(xin, wr);
    }
  }
  float tot = reduce8(smred, acc);
  {
    const int r2 = tid >> 5, b2 = tid & 31;
    const int rr = (r2>>1)*1024 + u0 + (r2&1);
    smg[r2*32 + b2] = tot + a.abih[rr] + a.abhh[rr];
  }
  __syncthreads();
  if (tid < 64) {
    const int u = tid >> 5, b2 = tid & 31;
    const int j = u0 + u;
    const float gi = smg[(0+u)*32+b2], gf = smg[(2+u)*32+b2];
    const float gg = smg[(4+u)*32+b2], go = smg[(6+u)*32+b2];
    const float c = sigf(gf)*acs[b2*1024+j] + sigf(gi)*ftanh(gg);
    acs[b2*1024+j] = c;
    ah_new[b2*1024+j] = sigf(go)*ftanh(c);
  }
}

// ======== merged dec-LSTM gate GEMV: gpart = dh(s-1)@dWhh + ah(s)@dWih[:,:1024] + biases ========
// 4 rows per job g in [0,1024)
__device__ __forceinline__ void jg_job(const KArgs& a, float* sm, int s, int g) {
  const int tid = threadIdx.x;
  const int b = tid & 31, seg = tid >> 5;
  float* ws = a.ws;
  const u16* wb = a.wb;
  const float* dh = ws + OFF_DH;
  const float* ah = ws + OFF_AH + (((s) & 1) * 32768);
  float acc[4];
  #pragma unroll
  for (int r = 0; r < 4; ++r) acc[r] = 0.f;
  #pragma unroll 2
  for (int kc = 0; kc < 8; ++kc) {
    const float* src = (kc < 4) ? (dh + b*1024 + kc*256) : (ah + b*1024 + (kc-4)*256);
    float xin[32];
    loadx(src + seg*32, xin);
    #pragma unroll
    for (int r = 0; r < 4; ++r) {
      const int rr = g*4 + r;
      const u16* wr = (kc < 4) ? (wb + B_DWHH + rr*1024 + kc*256 + seg*32)
                               : (wb + B_DWIH + rr*1536 + (kc-4)*256 + seg*32);
      acc[r] += dot32b(xin, wr);
    }
  }
  __syncthreads();
  #pragma unroll
  for (int r = 0; r < 4; ++r) sm[(seg*4 + r)*32 + b] = acc[r];
  __syncthreads();
  if (tid < 128) {
    const int r2 = tid >> 5, b2 = tid & 31;
    const int rr = g*4 + r2;
    float tot = 0.f;
    #pragma unroll
    for (int sgi = 0; sgi < 8; ++sgi) tot += sm[(sgi*4 + r2)*32 + b2];
    ws[OFF_GPART + rr*32 + b2] = tot + a.dbih[rr] + a.dbhh[rr];
  }
}

// ======== P3: finish dec LSTM for step s (ctx columns + nonlinearity), u0 = 2*job ========
__device__ __forceinline__ void p3_job(const KArgs& a, float* sm, int s, int u0) {
  float* smred = sm;
  float* smg   = sm + 2048;
  const int tid = threadIdx.x;
  float* ws = a.ws;
  const u16* wb = a.wb;
  float* dh  = ws + OFF_DH;
  float* dcs = ws + OFF_DCS;
  const float* ctx = ws + OFF_CTX + (((s) & 1) * 16384);
  float* gpart = ws + OFF_GPART;

  const int b = tid & 31, seg = tid >> 5;
  float acc[8];
  #pragma unroll
  for (int r = 0; r < 8; ++r) acc[r] = 0.f;
  #pragma unroll 2
  for (int kc = 0; kc < 2; ++kc) {
    float xin[32];
    loadx(ctx + b*512 + kc*256 + seg*32, xin);
    #pragma unroll
    for (int r = 0; r < 8; ++r) {
      const int rr = (r>>1)*1024 + u0 + (r&1);
      acc[r] += dot32b(xin, wb + B_DWIH + rr*1536 + 1024 + kc*256 + seg*32);
    }
  }
  float tot = reduce8(smred, acc);
  {
    const int r2 = tid >> 5, b2 = tid & 31;
    const int rr = (r2>>1)*1024 + u0 + (r2&1);
    smg[r2*32 + b2] = tot + gpart[rr*32 + b2];
  }
  __syncthreads();
  if (tid < 64) {
    const int u = tid >> 5, b2 = tid & 31;
    const int j = u0 + u;
    const float gi = smg[(0+u)*32+b2], gf = smg[(2+u)*32+b2];
    const float gg = smg[(4+u)*32+b2], go = smg[(6+u)*32+b2];
    const float c = sigf(gf)*dcs[b2*1024+j] + sigf(gi)*ftanh(gg);
    dcs[b2*1024+j] = c;
    dh[b2*1024+j] = sigf(go)*ftanh(c);
  }
}

// ======== J4: static conv + log-prior for next DCA (one batch per job) ========
__device__ __forceinline__ void j4_job(const KArgs& a, float* sm, int b4) {
  const int tid = threadIdx.x;
  float* ws = a.ws;
  float* aw   = ws + OFF_AW;
  float* fbuf = ws + OFF_FBUF;
  float* pbuf = ws + OFF_PBUF;
  __syncthreads();
  if (tid < 224) sm[tid] = (tid >= 10 && tid < 210) ? aw[b4*TENC + tid - 10] : 0.f;
  __syncthreads();
  if (tid < 200) {
    #pragma unroll
    for (int j = 0; j < 8; ++j) {
      float p = 0.f;
      #pragma unroll
      for (int tau = 0; tau < 21; ++tau) p += sm[tid + tau] * a.F[j*21 + tau];
      fbuf[(b4*TENC + tid)*8 + j] = p;
    }
    float pp = 0.f;
    #pragma unroll
    for (int tau = 0; tau < 11; ++tau) pp += sm[tid + tau] * a.prior[tau];
    pbuf[b4*TENC + tid] = __logf(fmaxf(pp, 1e-6f));
  }
}

// ======== init: zero state + one-hot aw + barrier flags ========
__global__ __launch_bounds__(NTHR) void init_kernel(KArgs a) {
  const int gtid = blockIdx.x*NTHR + threadIdx.x;
  const int str = gridDim.x*NTHR;
  float* ws = a.ws;
  if (gtid < 64) a.bar[gtid] = 0;
  for (int i = gtid; i < ZERO_CNT; i += str) ws[i] = 0.f;
  float* aw = ws + OFF_AW;
  for (int i = gtid; i < BATCH*TENC; i += str) aw[i] = ((i % TENC) == 0) ? 1.f : 0.f;
}

// ======== convert weights to bf16 (+ memory transpose) ========
__global__ __launch_bounds__(NTHR) void conv_kernel(KArgs a) {
  const int gtid = blockIdx.x*NTHR + threadIdx.x;
  const int str = gridDim.x*NTHR;
  u16* wb = a.wb;
  for (int i = gtid; i < 3145728; i += str) wb[B_AWIH + i] = f2b(a.aWih[i]);
  for (int i = gtid; i < 4194304; i += str) wb[B_AWHH + i] = f2b(a.aWhh[i]);
  for (int i = gtid; i < 6291456; i += str) wb[B_DWIH + i] = f2b(a.dWih[i]);
  for (int i = gtid; i < 4194304; i += str) wb[B_DWHH + i] = f2b(a.dWhh[i]);
  for (int i = gtid; i < 245760;  i += str) wb[B_ACW  + i] = f2b(a.acW[i]);
  for (int i = gtid; i < 131072;  i += str) wb[B_WQ   + i] = f2b(a.Wq[i]);
  for (int i = gtid; i < 3276800; i += str) {
    const int b = i / 102400, rem = i - b*102400;
    const int d = rem / 200, t = rem - d*200;
    wb[B_MEMT + i] = f2b(a.memory[b*102400 + t*512 + d]);
  }
}

// ======== prenet for all (s,b) pairs; grid 12800 ========
__global__ __launch_bounds__(NTHR) void prenet_kernel(KArgs a) {
  __shared__ float sm[384];
  const int tid = threadIdx.x;
  const int pair = blockIdx.x;           // s*32 + b
  const int s = pair >> 5, b = pair & 31;
  float* X = a.ws + OFF_X;
  if (tid < 80) {
    float v = 0.f;
    if (s > 0) v = a.mels[(b*NMELS + tid)*TMELS + 2*s - 1];
    sm[tid] = v;
  }
  __syncthreads();
  float a1 = a.pb1[tid];
  #pragma unroll 4
  for (int k = 0; k < 80; ++k) a1 += a.pW1[tid*80 + k] * sm[k];
  a1 = fmaxf(a1, 0.f);
  __syncthreads();
  sm[128 + tid] = a1;
  __syncthreads();
  float a2 = a.pb2[tid];
  #pragma unroll 4
  for (int k = 0; k < 256; ++k) a2 += a.pW2[tid*256 + k] * sm[128 + k];
  a2 = fmaxf(a2, 0.f);
  X[(s*BATCH + b)*256 + tid] = a2;
}

// ======== persistent loop: all 400 steps, software grid barrier, 2 barriers/step ========
// Phase A(s): DCA(s) [blocks 0..31] | outproj(s-1) [32..51] | gate GEMV [52..511 -> 1024 jobs]
// Phase B(s): J1(s+1) [all blocks] + P3(s) [all blocks] + J4(s+1) [blocks 480..511]
__global__ __launch_bounds__(NTHR, 2) void loop_kernel(KArgs a) {
  __shared__ float sm[5536];
  const int bid = blockIdx.x;
  float* ws = a.ws;
  int* bar = a.bar;
  bool bailed = false;

  // prologue: ah(0) = J1(0) (ctx(-1)=0, ah(-1)=0); fbuf/pbuf for step 0 from one-hot aw
  j1_job(a, sm, 0, bid*2);
  if (bid >= 480) j4_job(a, sm, bid - 480);
  gbar(bar, bailed);

  for (int s = 0; s < NSTEP; ++s) {
    // ---- phase A ----
    if (bid < 32) {
      dca_step(a, sm, bid, s,
               ws + OFF_AH  + (((s) & 1) * 32768),
               ws + OFF_AW, ws + OFF_FBUF, ws + OFF_PBUF,
               ws + OFF_CTX + (((s) & 1) * 16384));
    } else if (bid < 52) {
      if (s > 0) outproj(a, sm, ws + OFF_DH,
                         ws + OFF_CTX + (((s - 1) & 1) * 16384), bid - 32, s - 1);
    } else {
      for (int g = bid - 52; g < 1024; g += (NBLK - 52)) jg_job(a, sm, s, g);
    }
    gbar(bar, bailed);
    // ---- phase B ----
    if (s + 1 < NSTEP) j1_job(a, sm, s + 1, bid*2);
    p3_job(a, sm, s, bid*2);
    if (bid >= 480 && s + 1 < NSTEP) j4_job(a, sm, bid - 480);
    gbar(bar, bailed);
  }

  // epilogue: final step's output projection (dh(399), ctx(399) at parity 1)
  if (bid < 20) outproj(a, sm, ws + OFF_DH,
                        ws + OFF_CTX + (((NSTEP - 1) & 1) * 16384), bid, NSTEP - 1);
}

extern "C" void kernel_launch(void* const* d_in, const int* in_sizes, int n_in,
                              void* d_out, int out_size, void* d_ws, size_t ws_size,
                              hipStream_t stream) {
  (void)in_sizes; (void)n_in; (void)out_size; (void)ws_size;
  KArgs a;
  a.mels   = (const float*)d_in[0];
  a.memory = (const float*)d_in[1];
  a.pW1 = (const float*)d_in[2];  a.pb1 = (const float*)d_in[3];
  a.pW2 = (const float*)d_in[4];  a.pb2 = (const float*)d_in[5];
  a.aWih = (const float*)d_in[6]; a.aWhh = (const float*)d_in[7];
  a.abih = (const float*)d_in[8]; a.abhh = (const float*)d_in[9];
  a.Wq = (const float*)d_in[10];  a.bq = (const float*)d_in[11];
  a.V  = (const float*)d_in[12];  a.F  = (const float*)d_in[13];
  a.U  = (const float*)d_in[14];  a.T  = (const float*)d_in[15];
  a.Tb = (const float*)d_in[16];  a.vv = (const float*)d_in[17];
  a.prior = (const float*)d_in[18];
  a.dWih = (const float*)d_in[19]; a.dWhh = (const float*)d_in[20];
  a.dbih = (const float*)d_in[21]; a.dbhh = (const float*)d_in[22];
  a.acW  = (const float*)d_in[23]; a.acb  = (const float*)d_in[24];
  a.out = (float*)d_out;
  a.bar = (int*)d_ws;
  a.ws  = (float*)((char*)d_ws + 256);
  a.wb  = (u16*)(a.ws + FLOAT_END);

  hipLaunchKernelGGL(init_kernel, dim3(512), dim3(NTHR), 0, stream, a);
  hipLaunchKernelGGL(conv_kernel, dim3(2048), dim3(NTHR), 0, stream, a);
  hipLaunchKernelGGL(prenet_kernel, dim3(NSTEP*BATCH), dim3(NTHR), 0, stream, a);
  hipLaunchKernelGGL(loop_kernel, dim3(NBLK), dim3(NTHR), 0, stream, a);
}

// Round 3
// 107216.711 us; speedup vs baseline: 2.1556x; 2.1556x over previous
//
#include <hip/hip_runtime.h>
#include <hip/hip_bf16.h>

typedef unsigned short u16;
typedef unsigned int   u32;

#define NTHR 256
#define NBLK 512      // persistent grid: 2 blocks/CU * 256 CUs guaranteed resident

#define BATCH 32
#define TENC  200
#define NMELS 80
#define TMELS 800
#define NSTEP 400

// ---- ws float offsets (after 256B reserved region; barrier ints live in the reserved region) ----
#define OFF_AH    0          // 2 * 32*1024 double buffered: ah(s) lives at (s&1)
#define OFF_ACS   65536
#define OFF_DH    98304
#define OFF_DCS   131072
#define OFF_CTX   163840     // 2 * 32*512 double buffered: ctx(s) lives at (s&1)
#define OFF_AW    196608     // 32*200
#define OFF_FBUF  203008     // 32*200*8
#define OFF_PBUF  254208     // 32*200
#define OFF_GPART 260608     // 4096*32 ([row*32+b])
#define OFF_X     391680     // 400*32*256
#define FLOAT_END 3668480    // OFF_X + 3276800
#define ZERO_CNT  196608     // zero [0, OFF_AW)

// ---- bf16 region offsets (u16 indices, base = ws + FLOAT_END) ----
#define B_AWIH 0            // 4096*768
#define B_AWHH 3145728      // 4096*1024
#define B_DWIH 7340032      // 4096*1536
#define B_DWHH 13631488     // 4096*1024
#define B_ACW  17825792     // 160*1536
#define B_WQ   18071552     // 128*1024
#define B_MEMT 18202624     // 32*512*200  [b][d][t]

struct KArgs {
  const float *mels, *memory, *pW1, *pb1, *pW2, *pb2;
  const float *aWih, *aWhh, *abih, *abhh;
  const float *Wq, *bq, *V, *F, *U, *T, *Tb, *vv, *prior;
  const float *dWih, *dWhh, *dbih, *dbhh, *acW, *acb;
  float *out;
  float *ws;
  u16   *wb;
  int   *bar;
};

__device__ __forceinline__ float sigf(float x) {
  x = fminf(fmaxf(x, -30.f), 30.f);
  return 1.0f / (1.0f + __expf(-x));
}
__device__ __forceinline__ float ftanh(float x) {
  x = fminf(fmaxf(x, -15.f), 15.f);
  float e = __expf(2.f * x);
  return (e - 1.f) / (e + 1.f);
}
__device__ __forceinline__ float blo(u32 u) {
  union { u32 i; float f; } v; v.i = u << 16; return v.f;
}
__device__ __forceinline__ float bhi(u32 u) {
  union { u32 i; float f; } v; v.i = u & 0xffff0000u; return v.f;
}
__device__ __forceinline__ u16 f2b(float x) {
  __hip_bfloat16 h = __float2bfloat16(x);
  return *reinterpret_cast<u16*>(&h);
}

// ---- software grid barrier ----
// bar[0] = arrival counter, bar[1] = generation (monotonic).
// KEY PERF RULE (learned round 2): spin with RELAXED loads only — an agent-scope
// ACQUIRE per poll iteration emits cache invalidations that evict the weight
// working set chip-wide every step (measured: 16.5 GB HBM refetch, 67 GB/s eff).
// Exactly one release (arrival RMW) and one acquire (exit) per block per barrier.
__device__ __forceinline__ void gbar(int* bar, bool& bailed) {
  __syncthreads();
  if (threadIdx.x == 0 && !bailed) {
    int g = __hip_atomic_load(&bar[1], __ATOMIC_RELAXED, __HIP_MEMORY_SCOPE_AGENT);
    // ACQ_REL RMW: releases this block's writes; acquires all earlier arrivals'
    // releases (so the last block needs no extra acquire).
    int a = __hip_atomic_fetch_add(&bar[0], 1, __ATOMIC_ACQ_REL, __HIP_MEMORY_SCOPE_AGENT);
    if (a == NBLK - 1) {
      __hip_atomic_store(&bar[0], 0, __ATOMIC_RELAXED, __HIP_MEMORY_SCOPE_AGENT);
      __hip_atomic_store(&bar[1], g + 1, __ATOMIC_RELEASE, __HIP_MEMORY_SCOPE_AGENT);
    } else {
      int it = 0;
      while (__hip_atomic_load(&bar[1], __ATOMIC_RELAXED, __HIP_MEMORY_SCOPE_AGENT) == g) {
        __builtin_amdgcn_s_sleep(2);
        if (++it > (1 << 26)) { bailed = true; break; }
      }
      // single acquire: synchronizes-with the release store of gen (and,
      // transitively, every block's release arrival) — one invalidation total.
      (void)__hip_atomic_load(&bar[1], __ATOMIC_ACQUIRE, __HIP_MEMORY_SCOPE_AGENT);
    }
  }
  __syncthreads();
}

// direct activation load: 32 consecutive floats (16B-aligned)
__device__ __forceinline__ void loadx(const float* src, float* xin) {
  const float4* p = (const float4*)src;
  #pragma unroll
  for (int q = 0; q < 8; ++q) {
    float4 v = p[q];
    xin[q*4+0] = v.x; xin[q*4+1] = v.y; xin[q*4+2] = v.z; xin[q*4+3] = v.w;
  }
}

// 32-K dot with bf16 weight row-chunk (4 uint4 = 32 bf16)
__device__ __forceinline__ float dot32b(const float* xin, const u16* w) {
  const uint4* wp = (const uint4*)w;
  float acc = 0.f;
  #pragma unroll
  for (int q = 0; q < 4; ++q) {
    uint4 wv = wp[q];
    acc += blo(wv.x)*xin[q*8+0] + bhi(wv.x)*xin[q*8+1]
         + blo(wv.y)*xin[q*8+2] + bhi(wv.y)*xin[q*8+3]
         + blo(wv.z)*xin[q*8+4] + bhi(wv.z)*xin[q*8+5]
         + blo(wv.w)*xin[q*8+6] + bhi(wv.w)*xin[q*8+7];
  }
  return acc;
}

// per-(b,seg) acc[8] -> per-(r=t>>5, b=t&31) total; smred: 2048 floats
__device__ __forceinline__ float reduce8(float* smred, const float* acc) {
  const int t = threadIdx.x;
  const int b = t & 31, seg = t >> 5;
  __syncthreads();
  #pragma unroll
  for (int r = 0; r < 8; ++r) smred[(seg*8 + r)*32 + b] = acc[r];
  __syncthreads();
  const int r2 = t >> 5, b2 = t & 31;
  float tot = 0.f;
  #pragma unroll
  for (int sgi = 0; sgi < 8; ++sgi) tot += smred[(sgi*8 + r2)*32 + b2];
  return tot;
}

// output projection for step sprev (8 rows per job), bf16 acW
__device__ __forceinline__ void outproj(const KArgs& a, float* smred,
                                        const float* dh, const float* ctx,
                                        int pb, int sprev) {
  const int tid = threadIdx.x;
  const int b = tid & 31, seg = tid >> 5;
  const u16* wb = a.wb;
  float acc[8];
  #pragma unroll
  for (int r = 0; r < 8; ++r) acc[r] = 0.f;
  #pragma unroll 2
  for (int kc = 0; kc < 6; ++kc) {
    const float* src = (kc < 4) ? (dh + b*1024 + kc*256) : (ctx + b*512 + (kc-4)*256);
    float xin[32];
    loadx(src + seg*32, xin);
    #pragma unroll
    for (int r = 0; r < 8; ++r) {
      const int rr = pb*8 + r;
      acc[r] += dot32b(xin, wb + B_ACW + rr*1536 + kc*256 + seg*32);
    }
  }
  float tot = reduce8(smred, acc);
  const int r2 = tid >> 5, b2 = tid & 31;
  const int rr = pb*8 + r2;
  tot += a.acb[rr];
  a.out[(b2*NMELS + (rr >> 1))*TMELS + sprev*2 + (rr & 1)] = tot;
}

// ======== DCA (one block per batch) ========
__device__ __forceinline__ void dca_step(const KArgs& a, float* sm, int b, int s,
                                         const float* ah_new, float* aw,
                                         const float* fbuf, const float* pbuf, float* ctx) {
  const int tid = threadIdx.x;
  const u16* wb = a.wb;
  float* s_ah  = sm;            // 1024
  float* s_awp = sm + 1024;     // 224 (padded aw_prev)
  float* s_q   = sm + 1248;     // 128
  float* s_G   = sm + 1376;     // 176
  float* s_e   = sm + 1552;     // 208
  float* s_gg  = sm + 1760;     // 1600 [pos*8+d]
  float* s_ff  = sm + 3360;     // 1600 [pos*8+j]
  float* s_red = sm + 4960;     // 256
  float* s_awn = sm + 5216;     // 200
  for (int i = tid; i < 1024; i += NTHR) s_ah[i] = ah_new[b*1024 + i];
  if (tid < 220) s_awp[tid] = (tid >= 10 && tid < 210) ? aw[b*TENC + tid - 10] : 0.f;
  for (int i = tid; i < 1600; i += NTHR) s_ff[i] = fbuf[b*1600 + i];
  __syncthreads();
  // q = tanh(Wq @ ah + bq), bf16 Wq, split K across 2 halves
  {
    const int o = tid & 127, half = tid >> 7;
    const uint4* wq = (const uint4*)(wb + B_WQ + o*1024 + half*512);
    const float* xa = s_ah + half*512;
    float p = 0.f;
    #pragma unroll 8
    for (int q8 = 0; q8 < 64; ++q8) {
      uint4 w = wq[q8];
      const float* xq = xa + q8*8;
      p += blo(w.x)*xq[0] + bhi(w.x)*xq[1] + blo(w.y)*xq[2] + bhi(w.y)*xq[3]
         + blo(w.z)*xq[4] + bhi(w.z)*xq[5] + blo(w.w)*xq[6] + bhi(w.w)*xq[7];
    }
    s_red[tid] = p;
  }
  __syncthreads();
  if (tid < 128) s_q[tid] = ftanh(s_red[tid] + s_red[128 + tid] + a.bq[tid]);
  __syncthreads();
  // G = q @ V^T  (168 outputs, fp32 V)
  if (tid < 168) {
    const float4* vp = (const float4*)(a.V + tid*128);
    float p = 0.f;
    #pragma unroll
    for (int q4 = 0; q4 < 32; ++q4) {
      float4 w = vp[q4];
      const float* xq = s_q + q4*4;
      p += w.x*xq[0] + w.y*xq[1] + w.z*xq[2] + w.w*xq[3];
    }
    s_G[tid] = p;
  }
  __syncthreads();
  // dynamic conv: g[pos][d]
  for (int idx = tid; idx < 1600; idx += NTHR) {
    const int pos = idx >> 3, d = idx & 7;
    float p = 0.f;
    #pragma unroll
    for (int tau = 0; tau < 21; ++tau) p += s_awp[pos + tau] * s_G[d*21 + tau];
    s_gg[idx] = p;
  }
  __syncthreads();
  // energies: e[pos] = v . tanh(U f + T g + Tb) + p[pos]
  #pragma unroll 1
  for (int ro = 0; ro < 4; ++ro) {
    const int pos = ro*64 + (tid >> 2), sub = tid & 3;
    float av = 0.f;
    if (pos < 200) {
      const float* fpos = s_ff + pos*8;
      const float* gpos = s_gg + pos*8;
      #pragma unroll 4
      for (int fi = 0; fi < 32; ++fi) {
        const int ff = sub*32 + fi;
        const float4* Up = (const float4*)(a.U + ff*8);
        const float4* Tp = (const float4*)(a.T + ff*8);
        float4 u0 = Up[0], u1 = Up[1], t0 = Tp[0], t1 = Tp[1];
        float h = a.Tb[ff];
        h += u0.x*fpos[0] + u0.y*fpos[1] + u0.z*fpos[2] + u0.w*fpos[3]
           + u1.x*fpos[4] + u1.y*fpos[5] + u1.z*fpos[6] + u1.w*fpos[7];
        h += t0.x*gpos[0] + t0.y*gpos[1] + t0.z*gpos[2] + t0.w*gpos[3]
           + t1.x*gpos[4] + t1.y*gpos[5] + t1.z*gpos[6] + t1.w*gpos[7];
        av += a.vv[ff] * ftanh(h);
      }
    }
    av += __shfl_xor(av, 1);
    av += __shfl_xor(av, 2);
    if (sub == 0 && pos < 200) s_e[pos] = av + pbuf[b*TENC + pos];
  }
  __syncthreads();
  // softmax over 200
  float mval = (tid < 200) ? s_e[tid] : -1e30f;
  #pragma unroll
  for (int off = 32; off > 0; off >>= 1) mval = fmaxf(mval, __shfl_xor(mval, off));
  if ((tid & 63) == 0) s_red[tid >> 6] = mval;
  __syncthreads();
  const float m = fmaxf(fmaxf(s_red[0], s_red[1]), fmaxf(s_red[2], s_red[3]));
  const float ex = (tid < 200) ? __expf(s_e[tid] - m) : 0.f;
  float sv = ex;
  #pragma unroll
  for (int off = 32; off > 0; off >>= 1) sv += __shfl_xor(sv, off);
  if ((tid & 63) == 0) s_red[4 + (tid >> 6)] = sv;
  __syncthreads();
  const float inv = 1.f / (s_red[4] + s_red[5] + s_red[6] + s_red[7]);
  if (tid < 200) {
    const float awv = ex * inv;
    aw[b*TENC + tid] = awv;
    s_awn[tid] = awv;
    a.out[2048000 + b*80000 + tid*400 + s] = awv;
  }
  __syncthreads();
  // ctx = aw_new @ memory[b]   (bf16 memT [b][d][t], sequential uint4)
  #pragma unroll 1
  for (int d = tid; d < 512; d += NTHR) {
    const uint4* mp = (const uint4*)(wb + B_MEMT + b*102400 + d*200);
    float p = 0.f;
    #pragma unroll 5
    for (int q = 0; q < 25; ++q) {
      uint4 v = mp[q];
      const float* aa = s_awn + q*8;
      p += blo(v.x)*aa[0] + bhi(v.x)*aa[1] + blo(v.y)*aa[2] + bhi(v.y)*aa[3]
         + blo(v.z)*aa[4] + bhi(v.z)*aa[5] + blo(v.w)*aa[6] + bhi(v.w)*aa[7];
    }
    ctx[b*512 + d] = p;
  }
}

// ======== J1: attn LSTM for step s (u0 = 2*job, 2 units) ========
// reads ctx(s-1) = ctxbuf[(s+1)&1], ah(s-1) = ahbuf[(s+1)&1], X(s); writes ah(s) = ahbuf[s&1], acs
__device__ __forceinline__ void j1_job(const KArgs& a, float* sm, int s, int u0) {
  float* smred = sm;
  float* smg   = sm + 2048;
  const int tid = threadIdx.x;
  float* ws = a.ws;
  const u16* wb = a.wb;
  float* ah_prev = ws + OFF_AH + (((s + 1) & 1) * 32768);
  float* ah_new  = ws + OFF_AH + (((s) & 1) * 32768);
  float* acs = ws + OFF_ACS;
  const float* ctxp = ws + OFF_CTX + (((s + 1) & 1) * 16384);
  const float* Xs = ws + OFF_X + s * BATCH * 256;
  const int b = tid & 31, seg = tid >> 5;
  float acc[8];
  #pragma unroll
  for (int r = 0; r < 8; ++r) acc[r] = 0.f;
  #pragma unroll 2
  for (int kc = 0; kc < 7; ++kc) {
    const float* src = (kc < 2)  ? (ctxp + b*512 + kc*256)
                     : (kc == 2) ? (Xs + b*256)
                                 : (ah_prev + b*1024 + (kc-3)*256);
    float xin[32];
    loadx(src + seg*32, xin);
    #pragma unroll
    for (int r = 0; r < 8; ++r) {
      const int rr = (r>>1)*1024 + u0 + (r&1);
      const u16* wr = (kc < 3) ? (wb + B_AWIH + rr*768 + kc*256 + seg*32)
                               : (wb + B_AWHH + rr*1024 + (kc-3)*256 + seg*32);
      acc[r] += dot32b(xin, wr);
    }
  }
  float tot = reduce8(smred, acc);
  {
    const int r2 = tid >> 5, b2 = tid & 31;
    const int rr = (r2>>1)*1024 + u0 + (r2&1);
    smg[r2*32 + b2] = tot + a.abih[rr] + a.abhh[rr];
  }
  __syncthreads();
  if (tid < 64) {
    const int u = tid >> 5, b2 = tid & 31;
    const int j = u0 + u;
    const float gi = smg[(0+u)*32+b2], gf = smg[(2+u)*32+b2];
    const float gg = smg[(4+u)*32+b2], go = smg[(6+u)*32+b2];
    const float c = sigf(gf)*acs[b2*1024+j] + sigf(gi)*ftanh(gg);
    acs[b2*1024+j] = c;
    ah_new[b2*1024+j] = sigf(go)*ftanh(c);
  }
}

// ======== merged dec-LSTM gate GEMV: gpart = dh(s-1)@dWhh + ah(s)@dWih[:,:1024] + biases ========
// 4 rows per job g in [0,1024)
__device__ __forceinline__ void jg_job(const KArgs& a, float* sm, int s, int g) {
  const int tid = threadIdx.x;
  const int b = tid & 31, seg = tid >> 5;
  float* ws = a.ws;
  const u16* wb = a.wb;
  const float* dh = ws + OFF_DH;
  const float* ah = ws + OFF_AH + (((s) & 1) * 32768);
  float acc[4];
  #pragma unroll
  for (int r = 0; r < 4; ++r) acc[r] = 0.f;
  #pragma unroll 2
  for (int kc = 0; kc < 8; ++kc) {
    const float* src = (kc < 4) ? (dh + b*1024 + kc*256) : (ah + b*1024 + (kc-4)*256);
    float xin[32];
    loadx(src + seg*32, xin);
    #pragma unroll
    for (int r = 0; r < 4; ++r) {
      const int rr = g*4 + r;
      const u16* wr = (kc < 4) ? (wb + B_DWHH + rr*1024 + kc*256 + seg*32)
                               : (wb + B_DWIH + rr*1536 + (kc-4)*256 + seg*32);
      acc[r] += dot32b(xin, wr);
    }
  }
  __syncthreads();
  #pragma unroll
  for (int r = 0; r < 4; ++r) sm[(seg*4 + r)*32 + b] = acc[r];
  __syncthreads();
  if (tid < 128) {
    const int r2 = tid >> 5, b2 = tid & 31;
    const int rr = g*4 + r2;
    float tot = 0.f;
    #pragma unroll
    for (int sgi = 0; sgi < 8; ++sgi) tot += sm[(sgi*4 + r2)*32 + b2];
    ws[OFF_GPART + rr*32 + b2] = tot + a.dbih[rr] + a.dbhh[rr];
  }
}

// ======== P3: finish dec LSTM for step s (ctx columns + nonlinearity), u0 = 2*job ========
__device__ __forceinline__ void p3_job(const KArgs& a, float* sm, int s, int u0) {
  float* smred = sm;
  float* smg   = sm + 2048;
  const int tid = threadIdx.x;
  float* ws = a.ws;
  const u16* wb = a.wb;
  float* dh  = ws + OFF_DH;
  float* dcs = ws + OFF_DCS;
  const float* ctx = ws + OFF_CTX + (((s) & 1) * 16384);
  float* gpart = ws + OFF_GPART;

  const int b = tid & 31, seg = tid >> 5;
  float acc[8];
  #pragma unroll
  for (int r = 0; r < 8; ++r) acc[r] = 0.f;
  #pragma unroll 2
  for (int kc = 0; kc < 2; ++kc) {
    float xin[32];
    loadx(ctx + b*512 + kc*256 + seg*32, xin);
    #pragma unroll
    for (int r = 0; r < 8; ++r) {
      const int rr = (r>>1)*1024 + u0 + (r&1);
      acc[r] += dot32b(xin, wb + B_DWIH + rr*1536 + 1024 + kc*256 + seg*32);
    }
  }
  float tot = reduce8(smred, acc);
  {
    const int r2 = tid >> 5, b2 = tid & 31;
    const int rr = (r2>>1)*1024 + u0 + (r2&1);
    smg[r2*32 + b2] = tot + gpart[rr*32 + b2];
  }
  __syncthreads();
  if (tid < 64) {
    const int u = tid >> 5, b2 = tid & 31;
    const int j = u0 + u;
    const float gi = smg[(0+u)*32+b2], gf = smg[(2+u)*32+b2];
    const float gg = smg[(4+u)*32+b2], go = smg[(6+u)*32+b2];
    const float c = sigf(gf)*dcs[b2*1024+j] + sigf(gi)*ftanh(gg);
    dcs[b2*1024+j] = c;
    dh[b2*1024+j] = sigf(go)*ftanh(c);
  }
}

// ======== J4: static conv + log-prior for next DCA (one batch per job) ========
__device__ __forceinline__ void j4_job(const KArgs& a, float* sm, int b4) {
  const int tid = threadIdx.x;
  float* ws = a.ws;
  float* aw   = ws + OFF_AW;
  float* fbuf = ws + OFF_FBUF;
  float* pbuf = ws + OFF_PBUF;
  __syncthreads();
  if (tid < 224) sm[tid] = (tid >= 10 && tid < 210) ? aw[b4*TENC + tid - 10] : 0.f;
  __syncthreads();
  if (tid < 200) {
    #pragma unroll
    for (int j = 0; j < 8; ++j) {
      float p = 0.f;
      #pragma unroll
      for (int tau = 0; tau < 21; ++tau) p += sm[tid + tau] * a.F[j*21 + tau];
      fbuf[(b4*TENC + tid)*8 + j] = p;
    }
    float pp = 0.f;
    #pragma unroll
    for (int tau = 0; tau < 11; ++tau) pp += sm[tid + tau] * a.prior[tau];
    pbuf[b4*TENC + tid] = __logf(fmaxf(pp, 1e-6f));
  }
}

// ======== init: zero state + one-hot aw + barrier flags ========
__global__ __launch_bounds__(NTHR) void init_kernel(KArgs a) {
  const int gtid = blockIdx.x*NTHR + threadIdx.x;
  const int str = gridDim.x*NTHR;
  float* ws = a.ws;
  if (gtid < 64) a.bar[gtid] = 0;
  for (int i = gtid; i < ZERO_CNT; i += str) ws[i] = 0.f;
  float* aw = ws + OFF_AW;
  for (int i = gtid; i < BATCH*TENC; i += str) aw[i] = ((i % TENC) == 0) ? 1.f : 0.f;
}

// ======== convert weights to bf16 (+ memory transpose) ========
__global__ __launch_bounds__(NTHR) void conv_kernel(KArgs a) {
  const int gtid = blockIdx.x*NTHR + threadIdx.x;
  const int str = gridDim.x*NTHR;
  u16* wb = a.wb;
  for (int i = gtid; i < 3145728; i += str) wb[B_AWIH + i] = f2b(a.aWih[i]);
  for (int i = gtid; i < 4194304; i += str) wb[B_AWHH + i] = f2b(a.aWhh[i]);
  for (int i = gtid; i < 6291456; i += str) wb[B_DWIH + i] = f2b(a.dWih[i]);
  for (int i = gtid; i < 4194304; i += str) wb[B_DWHH + i] = f2b(a.dWhh[i]);
  for (int i = gtid; i < 245760;  i += str) wb[B_ACW  + i] = f2b(a.acW[i]);
  for (int i = gtid; i < 131072;  i += str) wb[B_WQ   + i] = f2b(a.Wq[i]);
  for (int i = gtid; i < 3276800; i += str) {
    const int b = i / 102400, rem = i - b*102400;
    const int d = rem / 200, t = rem - d*200;
    wb[B_MEMT + i] = f2b(a.memory[b*102400 + t*512 + d]);
  }
}

// ======== prenet for all (s,b) pairs; grid 12800 ========
__global__ __launch_bounds__(NTHR) void prenet_kernel(KArgs a) {
  __shared__ float sm[384];
  const int tid = threadIdx.x;
  const int pair = blockIdx.x;           // s*32 + b
  const int s = pair >> 5, b = pair & 31;
  float* X = a.ws + OFF_X;
  if (tid < 80) {
    float v = 0.f;
    if (s > 0) v = a.mels[(b*NMELS + tid)*TMELS + 2*s - 1];
    sm[tid] = v;
  }
  __syncthreads();
  float a1 = a.pb1[tid];
  #pragma unroll 4
  for (int k = 0; k < 80; ++k) a1 += a.pW1[tid*80 + k] * sm[k];
  a1 = fmaxf(a1, 0.f);
  __syncthreads();
  sm[128 + tid] = a1;
  __syncthreads();
  float a2 = a.pb2[tid];
  #pragma unroll 4
  for (int k = 0; k < 256; ++k) a2 += a.pW2[tid*256 + k] * sm[128 + k];
  a2 = fmaxf(a2, 0.f);
  X[(s*BATCH + b)*256 + tid] = a2;
}

// ======== persistent loop: all 400 steps, software grid barrier, 2 barriers/step ========
// Phase A(s): DCA(s) [blocks 0..31] | outproj(s-1) [32..51] | gate GEMV [52..511 -> 1024 jobs]
// Phase B(s): J1(s+1) [all blocks] + P3(s) [all blocks] + J4(s+1) [blocks 480..511]
__global__ __launch_bounds__(NTHR, 2) void loop_kernel(KArgs a) {
  __shared__ float sm[5536];
  const int bid = blockIdx.x;
  float* ws = a.ws;
  int* bar = a.bar;
  bool bailed = false;

  // prologue: ah(0) = J1(0) (ctx(-1)=0, ah(-1)=0); fbuf/pbuf for step 0 from one-hot aw
  j1_job(a, sm, 0, bid*2);
  if (bid >= 480) j4_job(a, sm, bid - 480);
  gbar(bar, bailed);

  for (int s = 0; s < NSTEP; ++s) {
    // ---- phase A ----
    if (bid < 32) {
      dca_step(a, sm, bid, s,
               ws + OFF_AH  + (((s) & 1) * 32768),
               ws + OFF_AW, ws + OFF_FBUF, ws + OFF_PBUF,
               ws + OFF_CTX + (((s) & 1) * 16384));
    } else if (bid < 52) {
      if (s > 0) outproj(a, sm, ws + OFF_DH,
                         ws + OFF_CTX + (((s - 1) & 1) * 16384), bid - 32, s - 1);
    } else {
      for (int g = bid - 52; g < 1024; g += (NBLK - 52)) jg_job(a, sm, s, g);
    }
    gbar(bar, bailed);
    // ---- phase B ----
    if (s + 1 < NSTEP) j1_job(a, sm, s + 1, bid*2);
    p3_job(a, sm, s, bid*2);
    if (bid >= 480 && s + 1 < NSTEP) j4_job(a, sm, bid - 480);
    gbar(bar, bailed);
  }

  // epilogue: final step's output projection (dh(399), ctx(399) at parity 1)
  if (bid < 20) outproj(a, sm, ws + OFF_DH,
                        ws + OFF_CTX + (((NSTEP - 1) & 1) * 16384), bid, NSTEP - 1);
}

extern "C" void kernel_launch(void* const* d_in, const int* in_sizes, int n_in,
                              void* d_out, int out_size, void* d_ws, size_t ws_size,
                              hipStream_t stream) {
  (void)in_sizes; (void)n_in; (void)out_size; (void)ws_size;
  KArgs a;
  a.mels   = (const float*)d_in[0];
  a.memory = (const float*)d_in[1];
  a.pW1 = (const float*)d_in[2];  a.pb1 = (const float*)d_in[3];
  a.pW2 = (const float*)d_in[4];  a.pb2 = (const float*)d_in[5];
  a.aWih = (const float*)d_in[6]; a.aWhh = (const float*)d_in[7];
  a.abih = (const float*)d_in[8]; a.abhh = (const float*)d_in[9];
  a.Wq = (const float*)d_in[10];  a.bq = (const float*)d_in[11];
  a.V  = (const float*)d_in[12];  a.F  = (const float*)d_in[13];
  a.U  = (const float*)d_in[14];  a.T  = (const float*)d_in[15];
  a.Tb = (const float*)d_in[16];  a.vv = (const float*)d_in[17];
  a.prior = (const float*)d_in[18];
  a.dWih = (const float*)d_in[19]; a.dWhh = (const float*)d_in[20];
  a.dbih = (const float*)d_in[21]; a.dbhh = (const float*)d_in[22];
  a.acW  = (const float*)d_in[23]; a.acb  = (const float*)d_in[24];
  a.out = (float*)d_out;
  a.bar = (int*)d_ws;
  a.ws  = (float*)((char*)d_ws + 256);
  a.wb  = (u16*)(a.ws + FLOAT_END);

  hipLaunchKernelGGL(init_kernel, dim3(512), dim3(NTHR), 0, stream, a);
  hipLaunchKernelGGL(conv_kernel, dim3(2048), dim3(NTHR), 0, stream, a);
  hipLaunchKernelGGL(prenet_kernel, dim3(NSTEP*BATCH), dim3(NTHR), 0, stream, a);
  hipLaunchKernelGGL(loop_kernel, dim3(NBLK), dim3(NTHR), 0, stream, a);
}

// Round 4
// 82040.564 us; speedup vs baseline: 2.8170x; 1.3069x over previous
//
#include <hip/hip_runtime.h>
#include <hip/hip_bf16.h>

typedef unsigned short u16;
typedef unsigned int   u32;

#define NTHR 256
#define NBLK 512      // persistent grid: 2 blocks/CU * 256 CUs guaranteed resident
#define NGRP 64
#define GRPSZ 8
#define ROOT (NBLK - 1)

#define BATCH 32
#define TENC  200
#define NMELS 80
#define TMELS 800
#define NSTEP 400

// ---- barrier int offsets within bar region (32 KB reserved at d_ws) ----
#define BAR_CNT(g)  ((g)*32)          // 64 counters, 128-B strided
#define BAR_FLAG(g) (2048 + (g)*32)   // 64 group flags, 128-B strided
#define BAR_GEN     4096              // root generation

// ---- ws float offsets (base = d_ws + 32768) ----
#define OFF_AH    0          // 2 * 32*1024 double buffered: ah(s) lives at (s&1)
#define OFF_ACS   65536
#define OFF_DH    98304
#define OFF_DCS   131072
#define OFF_CTX   163840     // 2 * 32*512 double buffered: ctx(s) lives at (s&1)
#define OFF_AW    196608     // 32*200
#define OFF_FBUF  203008     // 32*200*8
#define OFF_PBUF  254208     // 32*200
#define OFF_GPART 260608     // 4096*32 ([row*32+b])
#define OFF_X     391680     // 400*32*256
#define FLOAT_END 3668480    // OFF_X + 3276800
#define ZERO_CNT  196608     // zero [0, OFF_AW)

// ---- bf16 region offsets (u16 indices, base = ws + FLOAT_END) ----
#define B_AWIH 0            // 4096*768
#define B_AWHH 3145728      // 4096*1024
#define B_DWIH 7340032      // 4096*1536
#define B_DWHH 13631488     // 4096*1024
#define B_ACW  17825792     // 160*1536
#define B_WQ   18071552     // 128*1024
#define B_MEMT 18202624     // 32*512*200  [b][d][t]

struct KArgs {
  const float *mels, *memory, *pW1, *pb1, *pW2, *pb2;
  const float *aWih, *aWhh, *abih, *abhh;
  const float *Wq, *bq, *V, *F, *U, *T, *Tb, *vv, *prior;
  const float *dWih, *dWhh, *dbih, *dbhh, *acW, *acb;
  float *out;
  float *ws;
  u16   *wb;
  int   *bar;
};

__device__ __forceinline__ float sigf(float x) {
  x = fminf(fmaxf(x, -30.f), 30.f);
  return 1.0f / (1.0f + __expf(-x));
}
__device__ __forceinline__ float ftanh(float x) {
  x = fminf(fmaxf(x, -15.f), 15.f);
  float e = __expf(2.f * x);
  return (e - 1.f) / (e + 1.f);
}
__device__ __forceinline__ float blo(u32 u) {
  union { u32 i; float f; } v; v.i = u << 16; return v.f;
}
__device__ __forceinline__ float bhi(u32 u) {
  union { u32 i; float f; } v; v.i = u & 0xffff0000u; return v.f;
}
__device__ __forceinline__ u16 f2b(float x) {
  __hip_bfloat16 h = __float2bfloat16(x);
  return *reinterpret_cast<u16*>(&h);
}

// ---- hierarchical software grid barrier ----
// PERF RULES (learned r2/r3):
//  * spin with RELAXED loads only (acquire-per-poll = chip-wide invalidate storm)
//  * arrivals are RELEASE-only RMWs (writeback keeps clean weight lines in L2;
//    r3's ACQ_REL arrivals invalidated L2 512x/barrier -> 41 MB/step refetch)
//  * exactly ONE acquire (invalidate) per block per barrier, at exit
//  * tree: 8 serialized RMWs per 128-B-strided leaf line (r3: 512 on one line)
//  * root = block 511 (short job) polls 64 flags lane-parallel, flips GEN
__device__ __forceinline__ void gbar(int* bar, int* s_bail, int& gen) {
  const int tid = threadIdx.x;
  const int bid = blockIdx.x;
  const int t = ++gen;
  __syncthreads();
  if (!*s_bail) {
    if (tid == 0) {
      int a = __hip_atomic_fetch_add(&bar[BAR_CNT(bid >> 3)], 1,
                                     __ATOMIC_RELEASE, __HIP_MEMORY_SCOPE_AGENT);
      if (a == GRPSZ - 1) {
        __hip_atomic_store(&bar[BAR_CNT(bid >> 3)], 0, __ATOMIC_RELAXED, __HIP_MEMORY_SCOPE_AGENT);
        __hip_atomic_store(&bar[BAR_FLAG(bid >> 3)], t, __ATOMIC_RELEASE, __HIP_MEMORY_SCOPE_AGENT);
      }
    }
    if (bid == ROOT) {
      if (tid < NGRP) {
        int it = 0;
        while (__hip_atomic_load(&bar[BAR_FLAG(tid)], __ATOMIC_RELAXED, __HIP_MEMORY_SCOPE_AGENT) < t) {
          __builtin_amdgcn_s_sleep(1);
          if (++it > (1 << 24)) { *s_bail = 1; break; }
        }
      }
      __syncthreads();
      if (tid == 0) {
        __hip_atomic_store(&bar[BAR_GEN], t, __ATOMIC_RELEASE, __HIP_MEMORY_SCOPE_AGENT);
        (void)__hip_atomic_load(&bar[BAR_GEN], __ATOMIC_ACQUIRE, __HIP_MEMORY_SCOPE_AGENT);
      }
    } else {
      if (tid == 0) {
        int it = 0;
        while (__hip_atomic_load(&bar[BAR_GEN], __ATOMIC_RELAXED, __HIP_MEMORY_SCOPE_AGENT) < t) {
          __builtin_amdgcn_s_sleep(1);
          if (++it > (1 << 24)) { *s_bail = 1; break; }
        }
        (void)__hip_atomic_load(&bar[BAR_GEN], __ATOMIC_ACQUIRE, __HIP_MEMORY_SCOPE_AGENT);
      }
    }
  }
  __syncthreads();
}

// ---- post-barrier L2 warm: one u32 load per 64-B line, XOR-sunk (kept live) ----
__device__ __forceinline__ void pfrange(const void* p, int bytes, u32& pf) {
  const u32* q = (const u32*)p;
  const int nl = bytes >> 6;
  #pragma unroll 4
  for (int i = threadIdx.x; i < nl; i += NTHR) pf ^= q[i << 4];
}

// direct activation load: 32 consecutive floats (16B-aligned)
__device__ __forceinline__ void loadx(const float* src, float* xin) {
  const float4* p = (const float4*)src;
  #pragma unroll
  for (int q = 0; q < 8; ++q) {
    float4 v = p[q];
    xin[q*4+0] = v.x; xin[q*4+1] = v.y; xin[q*4+2] = v.z; xin[q*4+3] = v.w;
  }
}

// 32-K dot with bf16 weight row-chunk (4 uint4 = 32 bf16)
__device__ __forceinline__ float dot32b(const float* xin, const u16* w) {
  const uint4* wp = (const uint4*)w;
  float acc = 0.f;
  #pragma unroll
  for (int q = 0; q < 4; ++q) {
    uint4 wv = wp[q];
    acc += blo(wv.x)*xin[q*8+0] + bhi(wv.x)*xin[q*8+1]
         + blo(wv.y)*xin[q*8+2] + bhi(wv.y)*xin[q*8+3]
         + blo(wv.z)*xin[q*8+4] + bhi(wv.z)*xin[q*8+5]
         + blo(wv.w)*xin[q*8+6] + bhi(wv.w)*xin[q*8+7];
  }
  return acc;
}

// per-(b,seg) acc[8] -> per-(r=t>>5, b=t&31) total; smred: 2048 floats
__device__ __forceinline__ float reduce8(float* smred, const float* acc) {
  const int t = threadIdx.x;
  const int b = t & 31, seg = t >> 5;
  __syncthreads();
  #pragma unroll
  for (int r = 0; r < 8; ++r) smred[(seg*8 + r)*32 + b] = acc[r];
  __syncthreads();
  const int r2 = t >> 5, b2 = t & 31;
  float tot = 0.f;
  #pragma unroll
  for (int sgi = 0; sgi < 8; ++sgi) tot += smred[(sgi*8 + r2)*32 + b2];
  return tot;
}

// output projection for step sprev (8 rows per job), bf16 acW
__device__ __forceinline__ void outproj(const KArgs& a, float* smred,
                                        const float* dh, const float* ctx,
                                        int pb, int sprev) {
  const int tid = threadIdx.x;
  const int b = tid & 31, seg = tid >> 5;
  const u16* wb = a.wb;
  float acc[8];
  #pragma unroll
  for (int r = 0; r < 8; ++r) acc[r] = 0.f;
  #pragma unroll 2
  for (int kc = 0; kc < 6; ++kc) {
    const float* src = (kc < 4) ? (dh + b*1024 + kc*256) : (ctx + b*512 + (kc-4)*256);
    float xin[32];
    loadx(src + seg*32, xin);
    #pragma unroll
    for (int r = 0; r < 8; ++r) {
      const int rr = pb*8 + r;
      acc[r] += dot32b(xin, wb + B_ACW + rr*1536 + kc*256 + seg*32);
    }
  }
  float tot = reduce8(smred, acc);
  const int r2 = tid >> 5, b2 = tid & 31;
  const int rr = pb*8 + r2;
  tot += a.acb[rr];
  a.out[(b2*NMELS + (rr >> 1))*TMELS + sprev*2 + (rr & 1)] = tot;
}

// ======== DCA (one block per batch) ========
__device__ __forceinline__ void dca_step(const KArgs& a, float* sm, int b, int s,
                                         const float* ah_new, float* aw,
                                         const float* fbuf, const float* pbuf, float* ctx) {
  const int tid = threadIdx.x;
  const u16* wb = a.wb;
  float* s_ah  = sm;            // 1024
  float* s_awp = sm + 1024;     // 224 (padded aw_prev)
  float* s_q   = sm + 1248;     // 128
  float* s_G   = sm + 1376;     // 176
  float* s_e   = sm + 1552;     // 208
  float* s_gg  = sm + 1760;     // 1600 [pos*8+d]
  float* s_ff  = sm + 3360;     // 1600 [pos*8+j]
  float* s_red = sm + 4960;     // 256
  float* s_awn = sm + 5216;     // 200
  for (int i = tid; i < 1024; i += NTHR) s_ah[i] = ah_new[b*1024 + i];
  if (tid < 220) s_awp[tid] = (tid >= 10 && tid < 210) ? aw[b*TENC + tid - 10] : 0.f;
  for (int i = tid; i < 1600; i += NTHR) s_ff[i] = fbuf[b*1600 + i];
  __syncthreads();
  // q = tanh(Wq @ ah + bq), bf16 Wq, split K across 2 halves
  {
    const int o = tid & 127, half = tid >> 7;
    const uint4* wq = (const uint4*)(wb + B_WQ + o*1024 + half*512);
    const float* xa = s_ah + half*512;
    float p = 0.f;
    #pragma unroll 8
    for (int q8 = 0; q8 < 64; ++q8) {
      uint4 w = wq[q8];
      const float* xq = xa + q8*8;
      p += blo(w.x)*xq[0] + bhi(w.x)*xq[1] + blo(w.y)*xq[2] + bhi(w.y)*xq[3]
         + blo(w.z)*xq[4] + bhi(w.z)*xq[5] + blo(w.w)*xq[6] + bhi(w.w)*xq[7];
    }
    s_red[tid] = p;
  }
  __syncthreads();
  if (tid < 128) s_q[tid] = ftanh(s_red[tid] + s_red[128 + tid] + a.bq[tid]);
  __syncthreads();
  // G = q @ V^T  (168 outputs, fp32 V)
  if (tid < 168) {
    const float4* vp = (const float4*)(a.V + tid*128);
    float p = 0.f;
    #pragma unroll
    for (int q4 = 0; q4 < 32; ++q4) {
      float4 w = vp[q4];
      const float* xq = s_q + q4*4;
      p += w.x*xq[0] + w.y*xq[1] + w.z*xq[2] + w.w*xq[3];
    }
    s_G[tid] = p;
  }
  __syncthreads();
  // dynamic conv: g[pos][d]
  for (int idx = tid; idx < 1600; idx += NTHR) {
    const int pos = idx >> 3, d = idx & 7;
    float p = 0.f;
    #pragma unroll
    for (int tau = 0; tau < 21; ++tau) p += s_awp[pos + tau] * s_G[d*21 + tau];
    s_gg[idx] = p;
  }
  __syncthreads();
  // energies: e[pos] = v . tanh(U f + T g + Tb) + p[pos]
  #pragma unroll 1
  for (int ro = 0; ro < 4; ++ro) {
    const int pos = ro*64 + (tid >> 2), sub = tid & 3;
    float av = 0.f;
    if (pos < 200) {
      const float* fpos = s_ff + pos*8;
      const float* gpos = s_gg + pos*8;
      #pragma unroll 4
      for (int fi = 0; fi < 32; ++fi) {
        const int ff = sub*32 + fi;
        const float4* Up = (const float4*)(a.U + ff*8);
        const float4* Tp = (const float4*)(a.T + ff*8);
        float4 u0 = Up[0], u1 = Up[1], t0 = Tp[0], t1 = Tp[1];
        float h = a.Tb[ff];
        h += u0.x*fpos[0] + u0.y*fpos[1] + u0.z*fpos[2] + u0.w*fpos[3]
           + u1.x*fpos[4] + u1.y*fpos[5] + u1.z*fpos[6] + u1.w*fpos[7];
        h += t0.x*gpos[0] + t0.y*gpos[1] + t0.z*gpos[2] + t0.w*gpos[3]
           + t1.x*gpos[4] + t1.y*gpos[5] + t1.z*gpos[6] + t1.w*gpos[7];
        av += a.vv[ff] * ftanh(h);
      }
    }
    av += __shfl_xor(av, 1);
    av += __shfl_xor(av, 2);
    if (sub == 0 && pos < 200) s_e[pos] = av + pbuf[b*TENC + pos];
  }
  __syncthreads();
  // softmax over 200
  float mval = (tid < 200) ? s_e[tid] : -1e30f;
  #pragma unroll
  for (int off = 32; off > 0; off >>= 1) mval = fmaxf(mval, __shfl_xor(mval, off));
  if ((tid & 63) == 0) s_red[tid >> 6] = mval;
  __syncthreads();
  const float m = fmaxf(fmaxf(s_red[0], s_red[1]), fmaxf(s_red[2], s_red[3]));
  const float ex = (tid < 200) ? __expf(s_e[tid] - m) : 0.f;
  float sv = ex;
  #pragma unroll
  for (int off = 32; off > 0; off >>= 1) sv += __shfl_xor(sv, off);
  if ((tid & 63) == 0) s_red[4 + (tid >> 6)] = sv;
  __syncthreads();
  const float inv = 1.f / (s_red[4] + s_red[5] + s_red[6] + s_red[7]);
  if (tid < 200) {
    const float awv = ex * inv;
    aw[b*TENC + tid] = awv;
    s_awn[tid] = awv;
    a.out[2048000 + b*80000 + tid*400 + s] = awv;
  }
  __syncthreads();
  // ctx = aw_new @ memory[b]   (bf16 memT [b][d][t], sequential uint4)
  #pragma unroll 1
  for (int d = tid; d < 512; d += NTHR) {
    const uint4* mp = (const uint4*)(wb + B_MEMT + b*102400 + d*200);
    float p = 0.f;
    #pragma unroll 5
    for (int q = 0; q < 25; ++q) {
      uint4 v = mp[q];
      const float* aa = s_awn + q*8;
      p += blo(v.x)*aa[0] + bhi(v.x)*aa[1] + blo(v.y)*aa[2] + bhi(v.y)*aa[3]
         + blo(v.z)*aa[4] + bhi(v.z)*aa[5] + blo(v.w)*aa[6] + bhi(v.w)*aa[7];
    }
    ctx[b*512 + d] = p;
  }
}

// ======== J1: attn LSTM for step s (u0 = 2*job, 2 units) ========
__device__ __forceinline__ void j1_job(const KArgs& a, float* sm, int s, int u0) {
  float* smred = sm;
  float* smg   = sm + 2048;
  const int tid = threadIdx.x;
  float* ws = a.ws;
  const u16* wb = a.wb;
  float* ah_prev = ws + OFF_AH + (((s + 1) & 1) * 32768);
  float* ah_new  = ws + OFF_AH + (((s) & 1) * 32768);
  float* acs = ws + OFF_ACS;
  const float* ctxp = ws + OFF_CTX + (((s + 1) & 1) * 16384);
  const float* Xs = ws + OFF_X + s * BATCH * 256;
  const int b = tid & 31, seg = tid >> 5;
  float acc[8];
  #pragma unroll
  for (int r = 0; r < 8; ++r) acc[r] = 0.f;
  #pragma unroll 2
  for (int kc = 0; kc < 7; ++kc) {
    const float* src = (kc < 2)  ? (ctxp + b*512 + kc*256)
                     : (kc == 2) ? (Xs + b*256)
                                 : (ah_prev + b*1024 + (kc-3)*256);
    float xin[32];
    loadx(src + seg*32, xin);
    #pragma unroll
    for (int r = 0; r < 8; ++r) {
      const int rr = (r>>1)*1024 + u0 + (r&1);
      const u16* wr = (kc < 3) ? (wb + B_AWIH + rr*768 + kc*256 + seg*32)
                               : (wb + B_AWHH + rr*1024 + (kc-3)*256 + seg*32);
      acc[r] += dot32b(xin, wr);
    }
  }
  float tot = reduce8(smred, acc);
  {
    const int r2 = tid >> 5, b2 = tid & 31;
    const int rr = (r2>>1)*1024 + u0 + (r2&1);
    smg[r2*32 + b2] = tot + a.abih[rr] + a.abhh[rr];
  }
  __syncthreads();
  if (tid < 64) {
    const int u = tid >> 5, b2 = tid & 31;
    const int j = u0 + u;
    const float gi = smg[(0+u)*32+b2], gf = smg[(2+u)*32+b2];
    const float gg = smg[(4+u)*32+b2], go = smg[(6+u)*32+b2];
    const float c = sigf(gf)*acs[b2*1024+j] + sigf(gi)*ftanh(gg);
    acs[b2*1024+j] = c;
    ah_new[b2*1024+j] = sigf(go)*ftanh(c);
  }
}

// ======== merged dec-LSTM gate GEMV: gpart = dh(s-1)@dWhh + ah(s)@dWih[:,:1024] + biases ========
__device__ __forceinline__ void jg_job(const KArgs& a, float* sm, int s, int g) {
  const int tid = threadIdx.x;
  const int b = tid & 31, seg = tid >> 5;
  float* ws = a.ws;
  const u16* wb = a.wb;
  const float* dh = ws + OFF_DH;
  const float* ah = ws + OFF_AH + (((s) & 1) * 32768);
  float acc[4];
  #pragma unroll
  for (int r = 0; r < 4; ++r) acc[r] = 0.f;
  #pragma unroll 2
  for (int kc = 0; kc < 8; ++kc) {
    const float* src = (kc < 4) ? (dh + b*1024 + kc*256) : (ah + b*1024 + (kc-4)*256);
    float xin[32];
    loadx(src + seg*32, xin);
    #pragma unroll
    for (int r = 0; r < 4; ++r) {
      const int rr = g*4 + r;
      const u16* wr = (kc < 4) ? (wb + B_DWHH + rr*1024 + kc*256 + seg*32)
                               : (wb + B_DWIH + rr*1536 + (kc-4)*256 + seg*32);
      acc[r] += dot32b(xin, wr);
    }
  }
  __syncthreads();
  #pragma unroll
  for (int r = 0; r < 4; ++r) sm[(seg*4 + r)*32 + b] = acc[r];
  __syncthreads();
  if (tid < 128) {
    const int r2 = tid >> 5, b2 = tid & 31;
    const int rr = g*4 + r2;
    float tot = 0.f;
    #pragma unroll
    for (int sgi = 0; sgi < 8; ++sgi) tot += sm[(sgi*4 + r2)*32 + b2];
    ws[OFF_GPART + rr*32 + b2] = tot + a.dbih[rr] + a.dbhh[rr];
  }
}

// ======== P3: finish dec LSTM for step s (ctx columns + nonlinearity), u0 = 2*job ========
__device__ __forceinline__ void p3_job(const KArgs& a, float* sm, int s, int u0) {
  float* smred = sm;
  float* smg   = sm + 2048;
  const int tid = threadIdx.x;
  float* ws = a.ws;
  const u16* wb = a.wb;
  float* dh  = ws + OFF_DH;
  float* dcs = ws + OFF_DCS;
  const float* ctx = ws + OFF_CTX + (((s) & 1) * 16384);
  float* gpart = ws + OFF_GPART;

  const int b = tid & 31, seg = tid >> 5;
  float acc[8];
  #pragma unroll
  for (int r = 0; r < 8; ++r) acc[r] = 0.f;
  #pragma unroll 2
  for (int kc = 0; kc < 2; ++kc) {
    float xin[32];
    loadx(ctx + b*512 + kc*256 + seg*32, xin);
    #pragma unroll
    for (int r = 0; r < 8; ++r) {
      const int rr = (r>>1)*1024 + u0 + (r&1);
      acc[r] += dot32b(xin, wb + B_DWIH + rr*1536 + 1024 + kc*256 + seg*32);
    }
  }
  float tot = reduce8(smred, acc);
  {
    const int r2 = tid >> 5, b2 = tid & 31;
    const int rr = (r2>>1)*1024 + u0 + (r2&1);
    smg[r2*32 + b2] = tot + gpart[rr*32 + b2];
  }
  __syncthreads();
  if (tid < 64) {
    const int u = tid >> 5, b2 = tid & 31;
    const int j = u0 + u;
    const float gi = smg[(0+u)*32+b2], gf = smg[(2+u)*32+b2];
    const float gg = smg[(4+u)*32+b2], go = smg[(6+u)*32+b2];
    const float c = sigf(gf)*dcs[b2*1024+j] + sigf(gi)*ftanh(gg);
    dcs[b2*1024+j] = c;
    dh[b2*1024+j] = sigf(go)*ftanh(c);
  }
}

// ======== J4: static conv + log-prior for next DCA (one batch per job) ========
__device__ __forceinline__ void j4_job(const KArgs& a, float* sm, int b4) {
  const int tid = threadIdx.x;
  float* ws = a.ws;
  float* aw   = ws + OFF_AW;
  float* fbuf = ws + OFF_FBUF;
  float* pbuf = ws + OFF_PBUF;
  __syncthreads();
  if (tid < 224) sm[tid] = (tid >= 10 && tid < 210) ? aw[b4*TENC + tid - 10] : 0.f;
  __syncthreads();
  if (tid < 200) {
    #pragma unroll
    for (int j = 0; j < 8; ++j) {
      float p = 0.f;
      #pragma unroll
      for (int tau = 0; tau < 21; ++tau) p += sm[tid + tau] * a.F[j*21 + tau];
      fbuf[(b4*TENC + tid)*8 + j] = p;
    }
    float pp = 0.f;
    #pragma unroll
    for (int tau = 0; tau < 11; ++tau) pp += sm[tid + tau] * a.prior[tau];
    pbuf[b4*TENC + tid] = __logf(fmaxf(pp, 1e-6f));
  }
}

// ======== init: zero state + one-hot aw + barrier region ========
__global__ __launch_bounds__(NTHR) void init_kernel(KArgs a) {
  const int gtid = blockIdx.x*NTHR + threadIdx.x;
  const int str = gridDim.x*NTHR;
  float* ws = a.ws;
  for (int i = gtid; i < 8192; i += str) a.bar[i] = 0;
  for (int i = gtid; i < ZERO_CNT; i += str) ws[i] = 0.f;
  float* aw = ws + OFF_AW;
  for (int i = gtid; i < BATCH*TENC; i += str) aw[i] = ((i % TENC) == 0) ? 1.f : 0.f;
}

// ======== convert weights to bf16 (+ memory transpose) ========
__global__ __launch_bounds__(NTHR) void conv_kernel(KArgs a) {
  const int gtid = blockIdx.x*NTHR + threadIdx.x;
  const int str = gridDim.x*NTHR;
  u16* wb = a.wb;
  for (int i = gtid; i < 3145728; i += str) wb[B_AWIH + i] = f2b(a.aWih[i]);
  for (int i = gtid; i < 4194304; i += str) wb[B_AWHH + i] = f2b(a.aWhh[i]);
  for (int i = gtid; i < 6291456; i += str) wb[B_DWIH + i] = f2b(a.dWih[i]);
  for (int i = gtid; i < 4194304; i += str) wb[B_DWHH + i] = f2b(a.dWhh[i]);
  for (int i = gtid; i < 245760;  i += str) wb[B_ACW  + i] = f2b(a.acW[i]);
  for (int i = gtid; i < 131072;  i += str) wb[B_WQ   + i] = f2b(a.Wq[i]);
  for (int i = gtid; i < 3276800; i += str) {
    const int b = i / 102400, rem = i - b*102400;
    const int d = rem / 200, t = rem - d*200;
    wb[B_MEMT + i] = f2b(a.memory[b*102400 + t*512 + d]);
  }
}

// ======== prenet for all (s,b) pairs; grid 12800 ========
__global__ __launch_bounds__(NTHR) void prenet_kernel(KArgs a) {
  __shared__ float sm[384];
  const int tid = threadIdx.x;
  const int pair = blockIdx.x;           // s*32 + b
  const int s = pair >> 5, b = pair & 31;
  float* X = a.ws + OFF_X;
  if (tid < 80) {
    float v = 0.f;
    if (s > 0) v = a.mels[(b*NMELS + tid)*TMELS + 2*s - 1];
    sm[tid] = v;
  }
  __syncthreads();
  float a1 = a.pb1[tid];
  #pragma unroll 4
  for (int k = 0; k < 80; ++k) a1 += a.pW1[tid*80 + k] * sm[k];
  a1 = fmaxf(a1, 0.f);
  __syncthreads();
  sm[128 + tid] = a1;
  __syncthreads();
  float a2 = a.pb2[tid];
  #pragma unroll 4
  for (int k = 0; k < 256; ++k) a2 += a.pW2[tid*256 + k] * sm[128 + k];
  a2 = fmaxf(a2, 0.f);
  X[(s*BATCH + b)*256 + tid] = a2;
}

// ======== persistent loop: all 400 steps, tree barrier, 2 barriers/step ========
// Phase A(s): DCA(s) [blocks 0..31] | outproj(s-1) [32..51] | gate GEMV [52..511 -> 1024 jobs]
// Phase B(s): J1(s+1) [all blocks] + P3(s) [all blocks] + J4(s+1) [blocks 480..511]
__global__ __launch_bounds__(NTHR, 2) void loop_kernel(KArgs a) {
  __shared__ float sm[5536];
  __shared__ int s_bail;
  const int tid = threadIdx.x;
  const int bid = blockIdx.x;
  float* ws = a.ws;
  const u16* wb = a.wb;
  int* bar = a.bar;
  int gen = 0;
  u32 pf = 0;
  if (tid == 0) s_bail = 0;
  __syncthreads();

  // prologue: ah(0) = J1(0) (ctx(-1)=0, ah(-1)=0); fbuf/pbuf for step 0 from one-hot aw
  j1_job(a, sm, 0, bid*2);
  if (bid >= 480) j4_job(a, sm, bid - 480);
  gbar(bar, &s_bail, gen);

  for (int s = 0; s < NSTEP; ++s) {
    // ---- phase A ----
    if (bid < 32) {
      // warm L2 for memT[b] (needed at the END of DCA) + V while GEMV/softmax run
      pfrange(wb + B_MEMT + bid*102400, 204800, pf);
      pfrange(a.V, 168*128*4, pf);
      dca_step(a, sm, bid, s,
               ws + OFF_AH  + (((s) & 1) * 32768),
               ws + OFF_AW, ws + OFF_FBUF, ws + OFF_PBUF,
               ws + OFF_CTX + (((s) & 1) * 16384));
    } else if (bid < 52) {
      if (s > 0) {
        pfrange(wb + B_ACW + (bid-32)*8*1536, 8*1536*2, pf);
        outproj(a, sm, ws + OFF_DH,
                ws + OFF_CTX + (((s - 1) & 1) * 16384), bid - 32, s - 1);
      }
    } else {
      for (int g = bid - 52; g < 1024; g += (NBLK - 52)) {
        pfrange(wb + B_DWHH + g*4*1024, 4*1024*2, pf);
        pfrange(wb + B_DWIH + g*4*1536, 4*1536*2, pf);
      }
      for (int g = bid - 52; g < 1024; g += (NBLK - 52)) jg_job(a, sm, s, g);
    }
    gbar(bar, &s_bail, gen);
    // ---- phase B ----
    {
      const int u0 = bid*2;
      if (s + 1 < NSTEP) {
        #pragma unroll
        for (int gq = 0; gq < 4; ++gq) {
          pfrange(wb + B_AWIH + (gq*1024 + u0)*768, 2*768*2, pf);
          pfrange(wb + B_AWHH + (gq*1024 + u0)*1024, 2*1024*2, pf);
        }
      }
      #pragma unroll
      for (int r8 = 0; r8 < 8; ++r8) {
        const int rr = (r8 >> 1)*1024 + u0 + (r8 & 1);
        pfrange(wb + B_DWIH + rr*1536 + 1024, 512*2, pf);
      }
    }
    if (s + 1 < NSTEP) j1_job(a, sm, s + 1, bid*2);
    p3_job(a, sm, s, bid*2);
    if (bid >= 480 && s + 1 < NSTEP) j4_job(a, sm, bid - 480);
    gbar(bar, &s_bail, gen);
  }

  // epilogue: final step's output projection (dh(399), ctx(399) at parity 1)
  if (bid < 20) outproj(a, sm, ws + OFF_DH,
                        ws + OFF_CTX + (((NSTEP - 1) & 1) * 16384), bid, NSTEP - 1);
  asm volatile("" :: "v"(pf));   // keep prefetch loads live (rule #17)
}

extern "C" void kernel_launch(void* const* d_in, const int* in_sizes, int n_in,
                              void* d_out, int out_size, void* d_ws, size_t ws_size,
                              hipStream_t stream) {
  (void)in_sizes; (void)n_in; (void)out_size; (void)ws_size;
  KArgs a;
  a.mels   = (const float*)d_in[0];
  a.memory = (const float*)d_in[1];
  a.pW1 = (const float*)d_in[2];  a.pb1 = (const float*)d_in[3];
  a.pW2 = (const float*)d_in[4];  a.pb2 = (const float*)d_in[5];
  a.aWih = (const float*)d_in[6]; a.aWhh = (const float*)d_in[7];
  a.abih = (const float*)d_in[8]; a.abhh = (const float*)d_in[9];
  a.Wq = (const float*)d_in[10];  a.bq = (const float*)d_in[11];
  a.V  = (const float*)d_in[12];  a.F  = (const float*)d_in[13];
  a.U  = (const float*)d_in[14];  a.T  = (const float*)d_in[15];
  a.Tb = (const float*)d_in[16];  a.vv = (const float*)d_in[17];
  a.prior = (const float*)d_in[18];
  a.dWih = (const float*)d_in[19]; a.dWhh = (const float*)d_in[20];
  a.dbih = (const float*)d_in[21]; a.dbhh = (const float*)d_in[22];
  a.acW  = (const float*)d_in[23]; a.acb  = (const float*)d_in[24];
  a.out = (float*)d_out;
  a.bar = (int*)d_ws;
  a.ws  = (float*)((char*)d_ws + 32768);
  a.wb  = (u16*)(a.ws + FLOAT_END);

  hipLaunchKernelGGL(init_kernel, dim3(512), dim3(NTHR), 0, stream, a);
  hipLaunchKernelGGL(conv_kernel, dim3(2048), dim3(NTHR), 0, stream, a);
  hipLaunchKernelGGL(prenet_kernel, dim3(NSTEP*BATCH), dim3(NTHR), 0, stream, a);
  hipLaunchKernelGGL(loop_kernel, dim3(NBLK), dim3(NTHR), 0, stream, a);
}

// Round 5
// 58783.740 us; speedup vs baseline: 3.9316x; 1.3956x over previous
//
#include <hip/hip_runtime.h>
#include <hip/hip_bf16.h>

typedef unsigned short u16;
typedef unsigned int   u32;
typedef float f32x4 __attribute__((ext_vector_type(4)));

#define NTHR 256
#define NBLK 512      // persistent grid: 2 blocks/CU * 256 CUs guaranteed resident
#define NGRP 64
#define GRPSZ 8
#define ROOT (NBLK - 1)

#define BATCH 32
#define TENC  200
#define NMELS 80
#define TMELS 800
#define NSTEP 400

// ---- barrier int offsets within bar region (32 KB reserved at d_ws) ----
#define BAR_CNT(g)  ((g)*32)          // 64 counters, 128-B strided
#define BAR_FLAG(g) (2048 + (g)*32)   // 64 group flags, 128-B strided
#define BAR_GEN     4096              // root generation

// ---- ws float offsets (base = d_ws + 32768) ----
// ah/dh are CHUNKED: [parity][block(512)][64] where chunk = bsub*16 + ui
// (job bid = bg*64+ug owns units ug*16..+16, batches bg*4..+4).
// All cross-block regions are 128B-line disjoint per writer block.
#define OFF_AHC   0          // 2 * 32768
#define OFF_ACS   65536      // 512*64 (block-private)
#define OFF_DHC   98304      // 2 * 32768
#define OFF_DCS   163840     // 512*64 (block-private)
#define OFF_CTX   196608     // 2 * 32*512
#define OFF_AW    229376     // 32*224 (stride 224 = line multiple; block-private)
#define OFF_FBUF  236544     // 32*1600 (block-private)
#define OFF_PBUF  287744     // 32*224 (block-private)
#define OFF_GPC   294912     // 512 jobs * 256 (chunk per job)
#define OFF_X     425984     // 400*32*256 (read-only during loop)
#define FLOAT_END 3702784
#define ZERO_CNT  236544     // zero [0, OFF_FBUF)

// ---- bf16 region offsets (u16 indices, base = ws + FLOAT_END) ----
#define B_AWIH 0            // 4096*768   rows: gate*1024+unit, cols [ctx512|X256]
#define B_AWHH 3145728      // 4096*1024
#define B_DWIH 7340032      // 4096*1536  cols [ah1024|ctx512]
#define B_DWHH 13631488     // 4096*1024
#define B_ACW  17825792     // 160*1536   cols [dh1024|ctx512]
#define B_WQ   18071552     // 128*1024
#define B_MEMT 18202624     // 32*512*200  [b][d][t]

// NT = coherence-point load (bypass L1+L2). This is what makes the
// no-acquire barrier sound: consumers of cross-block data never read a
// (possibly stale) local cache line, so no invalidation is ever needed and
// the 43 MB weight set persists in L2 (r4 counters: acquires forced a
// 53 MB/step refetch at 300 GB/s = the whole bottleneck).
#define NTLD4(dst, src) \
  asm volatile("global_load_dwordx4 %0, %1, off sc0 sc1" : "=v"(dst) : "v"(src))
#define NTLD1(dst, src) \
  asm volatile("global_load_dword %0, %1, off sc0 sc1" : "=v"(dst) : "v"(src))
#define NTFENCE() do { \
  asm volatile("s_waitcnt vmcnt(0)" ::: "memory"); \
  __builtin_amdgcn_sched_barrier(0); } while (0)

struct KArgs {
  const float *mels, *memory, *pW1, *pb1, *pW2, *pb2;
  const float *aWih, *aWhh, *abih, *abhh;
  const float *Wq, *bq, *V, *F, *U, *T, *Tb, *vv, *prior;
  const float *dWih, *dWhh, *dbih, *dbhh, *acW, *acb;
  float *out;
  float *ws;
  u16   *wb;
  int   *bar;
};

__device__ __forceinline__ float sigf(float x) {
  x = fminf(fmaxf(x, -30.f), 30.f);
  return 1.0f / (1.0f + __expf(-x));
}
__device__ __forceinline__ float ftanh(float x) {
  x = fminf(fmaxf(x, -15.f), 15.f);
  float e = __expf(2.f * x);
  return (e - 1.f) / (e + 1.f);
}
__device__ __forceinline__ float blo(u32 u) {
  union { u32 i; float f; } v; v.i = u << 16; return v.f;
}
__device__ __forceinline__ float bhi(u32 u) {
  union { u32 i; float f; } v; v.i = u & 0xffff0000u; return v.f;
}
__device__ __forceinline__ u16 f2b(float x) {
  __hip_bfloat16 h = __float2bfloat16(x);
  return *reinterpret_cast<u16*>(&h);
}

// ---- tree grid barrier: releases only, NO acquires (NT reads replace them) ----
// spin RELAXED (r2 lesson); arrivals RELEASE (writeback keeps clean lines);
// consumers use sc0/sc1 loads for cross-block data so no invalidate needed.
__device__ __forceinline__ void gbar(int* bar, int* s_bail, int& gen) {
  const int tid = threadIdx.x;
  const int bid = blockIdx.x;
  const int t = ++gen;
  __syncthreads();
  if (!*s_bail) {
    if (tid == 0) {
      int a_ = __hip_atomic_fetch_add(&bar[BAR_CNT(bid >> 3)], 1,
                                      __ATOMIC_RELEASE, __HIP_MEMORY_SCOPE_AGENT);
      if (a_ == GRPSZ - 1) {
        __hip_atomic_store(&bar[BAR_CNT(bid >> 3)], 0, __ATOMIC_RELAXED, __HIP_MEMORY_SCOPE_AGENT);
        __hip_atomic_store(&bar[BAR_FLAG(bid >> 3)], t, __ATOMIC_RELEASE, __HIP_MEMORY_SCOPE_AGENT);
      }
    }
    if (bid == ROOT) {
      if (tid < NGRP) {
        int it = 0;
        while (__hip_atomic_load(&bar[BAR_FLAG(tid)], __ATOMIC_RELAXED, __HIP_MEMORY_SCOPE_AGENT) < t) {
          __builtin_amdgcn_s_sleep(1);
          if (++it > (1 << 24)) { *s_bail = 1; break; }
        }
      }
      __syncthreads();
      if (tid == 0)
        __hip_atomic_store(&bar[BAR_GEN], t, __ATOMIC_RELEASE, __HIP_MEMORY_SCOPE_AGENT);
    } else if (tid == 0) {
      int it = 0;
      while (__hip_atomic_load(&bar[BAR_GEN], __ATOMIC_RELAXED, __HIP_MEMORY_SCOPE_AGENT) < t) {
        __builtin_amdgcn_s_sleep(1);
        if (++it > (1 << 24)) { *s_bail = 1; break; }
      }
    }
  }
  __syncthreads();
}

// full-K dot: bf16 weights (L2-cached), fp32 x from LDS. K % 32 == 0.
__device__ __forceinline__ float dotK(const float* xs, const u16* w, int K) {
  const uint4* wp = (const uint4*)w;
  const float4* xp = (const float4*)xs;
  float a0 = 0.f, a1 = 0.f, a2 = 0.f, a3 = 0.f;
  #pragma unroll 2
  for (int i = 0; i < (K >> 5); ++i) {
    uint4 w0 = wp[i*4+0], w1 = wp[i*4+1], w2 = wp[i*4+2], w3 = wp[i*4+3];
    float4 x0 = xp[i*8+0], x1 = xp[i*8+1], x2 = xp[i*8+2], x3 = xp[i*8+3];
    float4 x4 = xp[i*8+4], x5 = xp[i*8+5], x6 = xp[i*8+6], x7 = xp[i*8+7];
    a0 += blo(w0.x)*x0.x + bhi(w0.x)*x0.y + blo(w0.y)*x0.z + bhi(w0.y)*x0.w
        + blo(w0.z)*x1.x + bhi(w0.z)*x1.y + blo(w0.w)*x1.z + bhi(w0.w)*x1.w;
    a1 += blo(w1.x)*x2.x + bhi(w1.x)*x2.y + blo(w1.y)*x2.z + bhi(w1.y)*x2.w
        + blo(w1.z)*x3.x + bhi(w1.z)*x3.y + blo(w1.w)*x3.z + bhi(w1.w)*x3.w;
    a2 += blo(w2.x)*x4.x + bhi(w2.x)*x4.y + blo(w2.y)*x4.z + bhi(w2.y)*x4.w
        + blo(w2.z)*x5.x + bhi(w2.z)*x5.y + blo(w2.w)*x5.z + bhi(w2.w)*x5.w;
    a3 += blo(w3.x)*x6.x + bhi(w3.x)*x6.y + blo(w3.y)*x6.z + bhi(w3.y)*x6.w
        + blo(w3.z)*x7.x + bhi(w3.z)*x7.y + blo(w3.w)*x7.z + bhi(w3.w)*x7.w;
  }
  return (a0 + a1) + (a2 + a3);
}

// ======== J1: attn LSTM step s; job = bid (ug=bid&63, bg=bid>>6) ========
__device__ __forceinline__ void j1_job(const KArgs& a, float* sm, int s) {
  const int tid = threadIdx.x, bid = blockIdx.x;
  const int ug = bid & 63, bg = bid >> 6;
  float* ws = a.ws;
  const u16* wb = a.wb;
  const int pprev = (s + 1) & 1, pcur = s & 1;
  const float* ctxp = ws + OFF_CTX + pprev * 16384;
  const float* ahp  = ws + OFF_AHC + pprev * 32768;
  const float* Xs   = ws + OFF_X + s * 8192;
  float* xbuf = sm;                 // 4 * 1800 (stride pad 8 -> bank offset)
  float* sred = sm + 8224;          // 256
  {
    const int bq = tid >> 6, lane = tid & 63;
    const int b = bg*4 + bq;
    const float* ctxb = ctxp + b*512;
    const float* Xb   = Xs + b*256;
    auto ap = [&](int idx) -> const f32x4* {
      if (idx < 128) return (const f32x4*)(ctxb + idx*4);
      if (idx < 192) return (const f32x4*)(Xb + (idx-128)*4);
      const int u = (idx-192)*4;
      return (const f32x4*)(ahp + (bg*64 + (u>>4))*64 + bq*16 + (u&15));
    };
    f32x4 v0,v1,v2,v3,v4,v5,v6;
    NTLD4(v0, ap(lane));       NTLD4(v1, ap(lane+64));
    NTLD4(v2, ap(lane+128));   NTLD4(v3, ap(lane+192));
    NTLD4(v4, ap(lane+256));   NTLD4(v5, ap(lane+320));
    NTLD4(v6, ap(lane+384));
    NTFENCE();
    f32x4* dst = (f32x4*)(xbuf + bq*1800);
    dst[lane] = v0; dst[lane+64] = v1; dst[lane+128] = v2; dst[lane+192] = v3;
    dst[lane+256] = v4; dst[lane+320] = v5; dst[lane+384] = v6;
  }
  __syncthreads();
  {
    const int r8 = tid >> 2, bsub = tid & 3;
    const int gate = r8 >> 4, ui = r8 & 15;
    const int rr = gate*1024 + ug*16 + ui;
    const float* xs = xbuf + bsub*1800;
    float acc = dotK(xs, wb + B_AWIH + rr*768, 768)
              + dotK(xs + 768, wb + B_AWHH + rr*1024, 1024)
              + a.abih[rr] + a.abhh[rr];
    sred[tid] = acc;
  }
  __syncthreads();
  if (tid < 64) {
    const int ui2 = tid >> 2, b2 = tid & 3;
    const float gi = sred[(ui2)*4 + b2];
    const float gf = sred[(16+ui2)*4 + b2];
    const float gg = sred[(32+ui2)*4 + b2];
    const float go = sred[(48+ui2)*4 + b2];
    float* acs = ws + OFF_ACS;
    const float c = sigf(gf)*acs[bid*64 + tid] + sigf(gi)*ftanh(gg);
    acs[bid*64 + tid] = c;
    (ws + OFF_AHC + pcur*32768)[bid*64 + b2*16 + ui2] = sigf(go)*ftanh(c);
  }
}

// ======== JG: dec-LSTM gates minus ctx part; job j on block 32+j (+448 doubles) ========
__device__ __forceinline__ void jg_job(const KArgs& a, float* sm, int s, int j) {
  const int tid = threadIdx.x;
  const int ug = j & 63, bg = j >> 6;
  float* ws = a.ws;
  const u16* wb = a.wb;
  const float* dhp = ws + OFF_DHC + ((s+1)&1)*32768;   // dh(s-1)
  const float* ahp = ws + OFF_AHC + (s&1)*32768;       // ah(s)
  float* xbuf = sm;                 // 4 * 2056
  __syncthreads();
  {
    const int bq = tid >> 6, lane = tid & 63;
    auto ap = [&](int idx) -> const f32x4* {
      if (idx < 256) { const int u = idx*4;
        return (const f32x4*)(dhp + (bg*64 + (u>>4))*64 + bq*16 + (u&15)); }
      const int u = (idx-256)*4;
      return (const f32x4*)(ahp + (bg*64 + (u>>4))*64 + bq*16 + (u&15));
    };
    f32x4 v0,v1,v2,v3,v4,v5,v6,v7;
    NTLD4(v0, ap(lane));       NTLD4(v1, ap(lane+64));
    NTLD4(v2, ap(lane+128));   NTLD4(v3, ap(lane+192));
    NTLD4(v4, ap(lane+256));   NTLD4(v5, ap(lane+320));
    NTLD4(v6, ap(lane+384));   NTLD4(v7, ap(lane+448));
    NTFENCE();
    f32x4* dst = (f32x4*)(xbuf + bq*2056);
    dst[lane] = v0; dst[lane+64] = v1; dst[lane+128] = v2; dst[lane+192] = v3;
    dst[lane+256] = v4; dst[lane+320] = v5; dst[lane+384] = v6; dst[lane+448] = v7;
  }
  __syncthreads();
  {
    const int r8 = tid >> 2, bsub = tid & 3;
    const int gate = r8 >> 4, ui = r8 & 15;
    const int rr = gate*1024 + ug*16 + ui;
    const float* xs = xbuf + bsub*2056;
    float acc = dotK(xs, wb + B_DWHH + rr*1024, 1024)
              + dotK(xs + 1024, wb + B_DWIH + rr*1536, 1024)
              + a.dbih[rr] + a.dbhh[rr];
    (ws + OFF_GPC)[j*256 + tid] = acc;
  }
}

// ======== P3: finish dec LSTM step s; job = bid ========
__device__ __forceinline__ void p3_job(const KArgs& a, float* sm, int s) {
  const int tid = threadIdx.x, bid = blockIdx.x;
  const int ug = bid & 63, bg = bid >> 6;
  float* ws = a.ws;
  const u16* wb = a.wb;
  const float* ctxc = ws + OFF_CTX + (s&1)*16384;
  float* xbuf = sm;                 // 4 * 520
  float* sred = sm + 8224;
  __syncthreads();
  const int bq = tid >> 6, lane = tid & 63;
  const int b = bg*4 + bq;
  f32x4 v0, v1; float gp;
  NTLD4(v0, (const f32x4*)(ctxc + b*512 + lane*4));
  NTLD4(v1, (const f32x4*)(ctxc + b*512 + (lane+64)*4));
  NTLD1(gp, (ws + OFF_GPC + bid*256 + tid));
  NTFENCE();
  ((f32x4*)(xbuf + bq*520))[lane] = v0;
  ((f32x4*)(xbuf + bq*520))[lane+64] = v1;
  __syncthreads();
  {
    const int r8 = tid >> 2, bsub = tid & 3;
    const int gate = r8 >> 4, ui = r8 & 15;
    const int rr = gate*1024 + ug*16 + ui;
    (void)gate; (void)ui;
    float acc = dotK(xbuf + bsub*520, wb + B_DWIH + rr*1536 + 1024, 512) + gp;
    sred[tid] = acc;
  }
  __syncthreads();
  if (tid < 64) {
    const int ui2 = tid >> 2, b2 = tid & 3;
    const float gi = sred[(ui2)*4 + b2];
    const float gf = sred[(16+ui2)*4 + b2];
    const float gg = sred[(32+ui2)*4 + b2];
    const float go = sred[(48+ui2)*4 + b2];
    float* dcs = ws + OFF_DCS;
    const float c = sigf(gf)*dcs[bid*64 + tid] + sigf(gi)*ftanh(gg);
    dcs[bid*64 + tid] = c;
    (ws + OFF_DHC + (s&1)*32768)[bid*64 + b2*16 + ui2] = sigf(go)*ftanh(c);
  }
}

// ======== J4: static conv + log-prior for next step; block b = bid (0..31); private ========
__device__ __forceinline__ void j4_job(const KArgs& a, float* sm) {
  const int tid = threadIdx.x, b4 = blockIdx.x;
  float* ws = a.ws;
  float* aw   = ws + OFF_AW;
  float* fbuf = ws + OFF_FBUF;
  float* pbuf = ws + OFF_PBUF;
  __syncthreads();
  if (tid < 224) sm[tid] = (tid >= 10 && tid < 210) ? aw[b4*224 + tid - 10] : 0.f;
  __syncthreads();
  if (tid < 200) {
    #pragma unroll
    for (int j = 0; j < 8; ++j) {
      float p = 0.f;
      #pragma unroll
      for (int tau = 0; tau < 21; ++tau) p += sm[tid + tau] * a.F[j*21 + tau];
      fbuf[b4*1600 + tid*8 + j] = p;
    }
    float pp = 0.f;
    #pragma unroll
    for (int tau = 0; tau < 11; ++tau) pp += sm[tid + tau] * a.prior[tau];
    pbuf[b4*224 + tid] = __logf(fmaxf(pp, 1e-6f));
  }
}

// ======== outproj for step sprev; blocks 192..351: rg = (bid-192)>>3, bg = (bid-192)&7 ========
__device__ __forceinline__ void outproj_job(const KArgs& a, float* sm, int sprev) {
  const int tid = threadIdx.x, bid = blockIdx.x;
  const int og = bid - 192, rg = og >> 3, bg = og & 7;
  const int pdm = sprev & 1;
  float* ws = a.ws;
  const u16* wb = a.wb;
  const float* dhp  = ws + OFF_DHC + pdm*32768;
  const float* ctxp = ws + OFF_CTX + pdm*16384;
  float* xbuf = sm;                 // 4 * 1544
  float* sred = sm + 8224;
  __syncthreads();
  {
    const int bq = tid >> 6, lane = tid & 63;
    const int b = bg*4 + bq;
    auto ap = [&](int idx) -> const f32x4* {
      if (idx < 256) { const int u = idx*4;
        return (const f32x4*)(dhp + (bg*64 + (u>>4))*64 + bq*16 + (u&15)); }
      return (const f32x4*)(ctxp + b*512 + (idx-256)*4);
    };
    f32x4 v0,v1,v2,v3,v4,v5;
    NTLD4(v0, ap(lane));       NTLD4(v1, ap(lane+64));
    NTLD4(v2, ap(lane+128));   NTLD4(v3, ap(lane+192));
    NTLD4(v4, ap(lane+256));   NTLD4(v5, ap(lane+320));
    NTFENCE();
    f32x4* dst = (f32x4*)(xbuf + bq*1544);
    dst[lane] = v0; dst[lane+64] = v1; dst[lane+128] = v2; dst[lane+192] = v3;
    dst[lane+256] = v4; dst[lane+320] = v5;
  }
  __syncthreads();
  {
    const int kc = tid & 7, r = (tid >> 3) & 7, bq = tid >> 6;
    const int rr = rg*8 + r;
    float p = dotK(xbuf + bq*1544 + kc*192, wb + B_ACW + rr*1536 + kc*192, 192);
    sred[tid] = p;
  }
  __syncthreads();
  if (tid < 32) {
    const int bq2 = tid >> 3, r2 = tid & 7;
    const int rr2 = rg*8 + r2, b2 = bg*4 + bq2;
    float tot = a.acb[rr2];
    #pragma unroll
    for (int q = 0; q < 8; ++q) tot += sred[bq2*64 + r2*8 + q];
    a.out[(b2*NMELS + (rr2 >> 1))*TMELS + sprev*2 + (rr2 & 1)] = tot;
  }
}

// ======== DCA (blocks 0..31, b = bid) ========
__device__ __forceinline__ void dca_step(const KArgs& a, float* sm, int s) {
  const int tid = threadIdx.x, b = blockIdx.x;
  const u16* wb = a.wb;
  float* ws = a.ws;
  const int pc = s & 1;
  const float* ahp = ws + OFF_AHC + pc*32768;
  float* ctx  = ws + OFF_CTX + pc*16384;
  float* aw   = ws + OFF_AW;
  const float* fbuf = ws + OFF_FBUF;
  const float* pbuf = ws + OFF_PBUF;
  float* s_ah  = sm;            // 1024
  float* s_awp = sm + 1024;     // 224
  float* s_q   = sm + 1248;     // 128
  float* s_G   = sm + 1376;     // 176
  float* s_e   = sm + 1552;     // 208
  float* s_gg  = sm + 1760;     // 1600
  float* s_ff  = sm + 3360;     // 1600
  float* s_red = sm + 4960;     // 256
  float* s_awn = sm + 5216;     // 200
  f32x4 vah;
  {
    const int u = tid*4;
    NTLD4(vah, (const f32x4*)(ahp + ((b>>2)*64 + (u>>4))*64 + (b&3)*16 + (u&15)));
  }
  if (tid < 224) s_awp[tid] = (tid >= 10 && tid < 210) ? aw[b*224 + tid - 10] : 0.f;
  for (int i = tid; i < 1600; i += NTHR) s_ff[i] = fbuf[b*1600 + i];
  NTFENCE();
  *(f32x4*)(s_ah + tid*4) = vah;
  __syncthreads();
  // q = tanh(Wq @ ah + bq)
  {
    const int o = tid & 127, half = tid >> 7;
    const uint4* wq = (const uint4*)(wb + B_WQ + o*1024 + half*512);
    const float* xa = s_ah + half*512;
    float p = 0.f;
    #pragma unroll 8
    for (int q8 = 0; q8 < 64; ++q8) {
      uint4 w = wq[q8];
      const float* xq = xa + q8*8;
      p += blo(w.x)*xq[0] + bhi(w.x)*xq[1] + blo(w.y)*xq[2] + bhi(w.y)*xq[3]
         + blo(w.z)*xq[4] + bhi(w.z)*xq[5] + blo(w.w)*xq[6] + bhi(w.w)*xq[7];
    }
    s_red[tid] = p;
  }
  __syncthreads();
  if (tid < 128) s_q[tid] = ftanh(s_red[tid] + s_red[128 + tid] + a.bq[tid]);
  __syncthreads();
  if (tid < 168) {
    const float4* vp = (const float4*)(a.V + tid*128);
    float p = 0.f;
    #pragma unroll
    for (int q4 = 0; q4 < 32; ++q4) {
      float4 w = vp[q4];
      const float* xq = s_q + q4*4;
      p += w.x*xq[0] + w.y*xq[1] + w.z*xq[2] + w.w*xq[3];
    }
    s_G[tid] = p;
  }
  __syncthreads();
  for (int idx = tid; idx < 1600; idx += NTHR) {
    const int pos = idx >> 3, d = idx & 7;
    float p = 0.f;
    #pragma unroll
    for (int tau = 0; tau < 21; ++tau) p += s_awp[pos + tau] * s_G[d*21 + tau];
    s_gg[idx] = p;
  }
  __syncthreads();
  #pragma unroll 1
  for (int ro = 0; ro < 4; ++ro) {
    const int pos = ro*64 + (tid >> 2), sub = tid & 3;
    float av = 0.f;
    if (pos < 200) {
      const float* fpos = s_ff + pos*8;
      const float* gpos = s_gg + pos*8;
      #pragma unroll 4
      for (int fi = 0; fi < 32; ++fi) {
        const int ff = sub*32 + fi;
        const float4* Up = (const float4*)(a.U + ff*8);
        const float4* Tp = (const float4*)(a.T + ff*8);
        float4 u0 = Up[0], u1 = Up[1], t0 = Tp[0], t1 = Tp[1];
        float h = a.Tb[ff];
        h += u0.x*fpos[0] + u0.y*fpos[1] + u0.z*fpos[2] + u0.w*fpos[3]
           + u1.x*fpos[4] + u1.y*fpos[5] + u1.z*fpos[6] + u1.w*fpos[7];
        h += t0.x*gpos[0] + t0.y*gpos[1] + t0.z*gpos[2] + t0.w*gpos[3]
           + t1.x*gpos[4] + t1.y*gpos[5] + t1.z*gpos[6] + t1.w*gpos[7];
        av += a.vv[ff] * ftanh(h);
      }
    }
    av += __shfl_xor(av, 1);
    av += __shfl_xor(av, 2);
    if (sub == 0 && pos < 200) s_e[pos] = av + pbuf[b*224 + pos];
  }
  __syncthreads();
  float mval = (tid < 200) ? s_e[tid] : -1e30f;
  #pragma unroll
  for (int off = 32; off > 0; off >>= 1) mval = fmaxf(mval, __shfl_xor(mval, off));
  if ((tid & 63) == 0) s_red[tid >> 6] = mval;
  __syncthreads();
  const float m = fmaxf(fmaxf(s_red[0], s_red[1]), fmaxf(s_red[2], s_red[3]));
  const float ex = (tid < 200) ? __expf(s_e[tid] - m) : 0.f;
  float sv = ex;
  #pragma unroll
  for (int off = 32; off > 0; off >>= 1) sv += __shfl_xor(sv, off);
  if ((tid & 63) == 0) s_red[4 + (tid >> 6)] = sv;
  __syncthreads();
  const float inv = 1.f / (s_red[4] + s_red[5] + s_red[6] + s_red[7]);
  if (tid < 200) {
    const float awv = ex * inv;
    aw[b*224 + tid] = awv;
    s_awn[tid] = awv;
    a.out[2048000 + b*80000 + tid*400 + s] = awv;
  }
  __syncthreads();
  #pragma unroll 1
  for (int d = tid; d < 512; d += NTHR) {
    const uint4* mp = (const uint4*)(wb + B_MEMT + b*102400 + d*200);
    float p = 0.f;
    #pragma unroll 5
    for (int q = 0; q < 25; ++q) {
      uint4 v = mp[q];
      const float* aa = s_awn + q*8;
      p += blo(v.x)*aa[0] + bhi(v.x)*aa[1] + blo(v.y)*aa[2] + bhi(v.y)*aa[3]
         + blo(v.z)*aa[4] + bhi(v.z)*aa[5] + blo(v.w)*aa[6] + bhi(v.w)*aa[7];
    }
    ctx[b*512 + d] = p;
  }
}

// ======== init: zero state + one-hot aw + barrier region ========
__global__ __launch_bounds__(NTHR) void init_kernel(KArgs a) {
  const int gtid = blockIdx.x*NTHR + threadIdx.x;
  const int str = gridDim.x*NTHR;
  float* ws = a.ws;
  for (int i = gtid; i < 8192; i += str) a.bar[i] = 0;
  for (int i = gtid; i < ZERO_CNT; i += str) ws[i] = 0.f;
  float* aw = ws + OFF_AW;
  for (int i = gtid; i < 32*224; i += str) aw[i] = ((i % 224) == 0) ? 1.f : 0.f;
}

// ======== convert weights to bf16 (+ memory transpose) ========
__global__ __launch_bounds__(NTHR) void conv_kernel(KArgs a) {
  const int gtid = blockIdx.x*NTHR + threadIdx.x;
  const int str = gridDim.x*NTHR;
  u16* wb = a.wb;
  for (int i = gtid; i < 3145728; i += str) wb[B_AWIH + i] = f2b(a.aWih[i]);
  for (int i = gtid; i < 4194304; i += str) wb[B_AWHH + i] = f2b(a.aWhh[i]);
  for (int i = gtid; i < 6291456; i += str) wb[B_DWIH + i] = f2b(a.dWih[i]);
  for (int i = gtid; i < 4194304; i += str) wb[B_DWHH + i] = f2b(a.dWhh[i]);
  for (int i = gtid; i < 245760;  i += str) wb[B_ACW  + i] = f2b(a.acW[i]);
  for (int i = gtid; i < 131072;  i += str) wb[B_WQ   + i] = f2b(a.Wq[i]);
  for (int i = gtid; i < 3276800; i += str) {
    const int b = i / 102400, rem = i - b*102400;
    const int d = rem / 200, t = rem - d*200;
    wb[B_MEMT + i] = f2b(a.memory[b*102400 + t*512 + d]);
  }
}

// ======== prenet for all (s,b) pairs; grid 12800 ========
__global__ __launch_bounds__(NTHR) void prenet_kernel(KArgs a) {
  __shared__ float sm[384];
  const int tid = threadIdx.x;
  const int pair = blockIdx.x;           // s*32 + b
  const int s = pair >> 5, b = pair & 31;
  float* X = a.ws + OFF_X;
  if (tid < 80) {
    float v = 0.f;
    if (s > 0) v = a.mels[(b*NMELS + tid)*TMELS + 2*s - 1];
    sm[tid] = v;
  }
  __syncthreads();
  float a1 = a.pb1[tid];
  #pragma unroll 4
  for (int k = 0; k < 80; ++k) a1 += a.pW1[tid*80 + k] * sm[k];
  a1 = fmaxf(a1, 0.f);
  __syncthreads();
  sm[128 + tid] = a1;
  __syncthreads();
  float a2 = a.pb2[tid];
  #pragma unroll 4
  for (int k = 0; k < 256; ++k) a2 += a.pW2[tid*256 + k] * sm[128 + k];
  a2 = fmaxf(a2, 0.f);
  X[(s*BATCH + b)*256 + tid] = a2;
}

// ======== persistent loop: 2 barriers/step ========
// alpha(s): DCA(s) [0..31] | JG(s) jobs [32..511; 32..63 doubled]
// beta(s):  J1(s+1) + P3(s) [all] | J4(s+1) [0..31] | outproj(s-1) [192..351]
__global__ __launch_bounds__(NTHR, 2) void loop_kernel(KArgs a) {
  __shared__ float sm[8480];
  __shared__ int s_bail;
  const int tid = threadIdx.x;
  const int bid = blockIdx.x;
  int* bar = a.bar;
  int gen = 0;
  if (tid == 0) s_bail = 0;
  __syncthreads();

  // prologue: J1(0) on all blocks; J4(step 0) on 0..31
  j1_job(a, sm, 0);
  if (bid < 32) j4_job(a, sm);
  gbar(bar, &s_bail, gen);

  for (int s = 0; s < NSTEP; ++s) {
    // ---- alpha ----
    if (bid < 32) {
      dca_step(a, sm, s);
    } else {
      jg_job(a, sm, s, bid - 32);
      if (bid < 64) jg_job(a, sm, s, bid + 448);
    }
    gbar(bar, &s_bail, gen);
    // ---- beta ----
    if (s + 1 < NSTEP) j1_job(a, sm, s + 1);
    p3_job(a, sm, s);
    if (bid < 32 && s + 1 < NSTEP) j4_job(a, sm);
    if (bid >= 192 && bid < 352 && s > 0) outproj_job(a, sm, s - 1);
    gbar(bar, &s_bail, gen);
  }

  // epilogue: final output projection
  if (bid >= 192 && bid < 352) outproj_job(a, sm, NSTEP - 1);
}

extern "C" void kernel_launch(void* const* d_in, const int* in_sizes, int n_in,
                              void* d_out, int out_size, void* d_ws, size_t ws_size,
                              hipStream_t stream) {
  (void)in_sizes; (void)n_in; (void)out_size; (void)ws_size;
  KArgs a;
  a.mels   = (const float*)d_in[0];
  a.memory = (const float*)d_in[1];
  a.pW1 = (const float*)d_in[2];  a.pb1 = (const float*)d_in[3];
  a.pW2 = (const float*)d_in[4];  a.pb2 = (const float*)d_in[5];
  a.aWih = (const float*)d_in[6]; a.aWhh = (const float*)d_in[7];
  a.abih = (const float*)d_in[8]; a.abhh = (const float*)d_in[9];
  a.Wq = (const float*)d_in[10];  a.bq = (const float*)d_in[11];
  a.V  = (const float*)d_in[12];  a.F  = (const float*)d_in[13];
  a.U  = (const float*)d_in[14];  a.T  = (const float*)d_in[15];
  a.Tb = (const float*)d_in[16];  a.vv = (const float*)d_in[17];
  a.prior = (const float*)d_in[18];
  a.dWih = (const float*)d_in[19]; a.dWhh = (const float*)d_in[20];
  a.dbih = (const float*)d_in[21]; a.dbhh = (const float*)d_in[22];
  a.acW  = (const float*)d_in[23]; a.acb  = (const float*)d_in[24];
  a.out = (float*)d_out;
  a.bar = (int*)d_ws;
  a.ws  = (float*)((char*)d_ws + 32768);
  a.wb  = (u16*)(a.ws + FLOAT_END);

  hipLaunchKernelGGL(init_kernel, dim3(512), dim3(NTHR), 0, stream, a);
  hipLaunchKernelGGL(conv_kernel, dim3(2048), dim3(NTHR), 0, stream, a);
  hipLaunchKernelGGL(prenet_kernel, dim3(NSTEP*BATCH), dim3(NTHR), 0, stream, a);
  hipLaunchKernelGGL(loop_kernel, dim3(NBLK), dim3(NTHR), 0, stream, a);
}

// Round 6
// 57431.604 us; speedup vs baseline: 4.0241x; 1.0235x over previous
//
#include <hip/hip_runtime.h>
#include <hip/hip_bf16.h>

typedef unsigned short u16;
typedef unsigned int   u32;
typedef float f32x4 __attribute__((ext_vector_type(4)));

#define NTHR 256
#define NBLK 512      // persistent grid: 2 blocks/CU * 256 CUs guaranteed resident
#define NGRP 64
#define GRPSZ 8
#define ROOT (NBLK - 1)

#define BATCH 32
#define TENC  200
#define NMELS 80
#define TMELS 800
#define NSTEP 400

// ---- barrier int offsets within bar region (32 KB reserved at d_ws) ----
#define BAR_CNT(g)  ((g)*32)          // 64 counters, 128-B strided
#define BAR_FLAG(g) (2048 + (g)*32)   // 64 group flags, 128-B strided
#define BAR_GEN     4096              // root generation

// ---- ws float offsets (base = d_ws + 32768) ----
// ah/dh CHUNKED: [parity][chunk W][64], chunk = bsub*16 + ui.
// Writer block for (ug,bg) is W(ug,bg) = (ug>>3) + 8*bg + 64*(ug&7)  [XCD-local
// mapping: all 8 bg-jobs for the same rows share bid%8 = same XCD -> rows are
// fetched ONCE per XCD per step and persist in that XCD's L2. r5 counters:
// old mapping spread same-row jobs over all 8 XCDs -> 35MB/step/XCD thrash.]
#define OFF_AHC   0          // 2 * 32768
#define OFF_ACS   65536      // 512*64 (block-private)
#define OFF_DHC   98304      // 2 * 32768
#define OFF_DCS   163840     // 512*64 (block-private)
#define OFF_CTX   196608     // 2 * 32*512
#define OFF_AW    229376     // 32*224 (block-private)
#define OFF_FBUF  236544     // 32*1600 (block-private)
#define OFF_PBUF  287744     // 32*224 (block-private)
#define OFF_GPC   294912     // 512 jobs * 256 (chunk per job)
#define OFF_X     425984     // 400*32*256 (immutable during loop -> cached loads)
#define FLOAT_END 3702784
#define ZERO_CNT  236544     // zero [0, OFF_FBUF)

// ---- bf16 region offsets (u16 indices, base = ws + FLOAT_END) ----
#define B_AWIH 0            // 4096*768   rows: gate*1024+unit, cols [ctx512|X256]
#define B_AWHH 3145728      // 4096*1024
#define B_DWIH 7340032      // 4096*1536  cols [ah1024|ctx512]
#define B_DWHH 13631488     // 4096*1024
#define B_ACW  17825792     // 160*1536   cols [dh1024|ctx512]
#define B_WQ   18071552     // 128*1024
#define B_MEMT 18202624     // 32*512*200  [b][d][t]

// NT = coherence-point load (bypass L1+L2): consumers of cross-block data never
// read stale cache lines, so barriers need NO acquire/invalidate and weights
// persist in L2 (r4/r5 lesson).
#define NTLD4(dst, src) \
  asm volatile("global_load_dwordx4 %0, %1, off sc0 sc1" : "=v"(dst) : "v"(src))
#define NTLD1(dst, src) \
  asm volatile("global_load_dword %0, %1, off sc0 sc1" : "=v"(dst) : "v"(src))
#define NTFENCE() do { \
  asm volatile("s_waitcnt vmcnt(0)" ::: "memory"); \
  __builtin_amdgcn_sched_barrier(0); } while (0)

struct KArgs {
  const float *mels, *memory, *pW1, *pb1, *pW2, *pb2;
  const float *aWih, *aWhh, *abih, *abhh;
  const float *Wq, *bq, *V, *F, *U, *T, *Tb, *vv, *prior;
  const float *dWih, *dWhh, *dbih, *dbhh, *acW, *acb;
  float *out;
  float *ws;
  u16   *wb;
  int   *bar;
};

__device__ __forceinline__ float frcp(float x) { return __builtin_amdgcn_rcpf(x); }
__device__ __forceinline__ float sigf(float x) {
  x = fminf(fmaxf(x, -30.f), 30.f);
  return frcp(1.0f + __expf(-x));
}
__device__ __forceinline__ float ftanh(float x) {
  x = fminf(fmaxf(x, -15.f), 15.f);
  float e = __expf(2.f * x);
  return (e - 1.f) * frcp(e + 1.f);
}
__device__ __forceinline__ float blo(u32 u) {
  union { u32 i; float f; } v; v.i = u << 16; return v.f;
}
__device__ __forceinline__ float bhi(u32 u) {
  union { u32 i; float f; } v; v.i = u & 0xffff0000u; return v.f;
}
__device__ __forceinline__ u16 f2b(float x) {
  __hip_bfloat16 h = __float2bfloat16(x);
  return *reinterpret_cast<u16*>(&h);
}
// chunk base (float offset) of (ug,bg) in the ah/dh chunked layout
__device__ __forceinline__ int chunkW(int ug_, int bg_) {
  return ((ug_ >> 3) + 8*bg_ + 64*(ug_ & 7)) * 64;
}

// ---- tree grid barrier: releases only, NO acquires ----
__device__ __forceinline__ void gbar(int* bar, int* s_bail, int& gen) {
  const int tid = threadIdx.x;
  const int bid = blockIdx.x;
  const int t = ++gen;
  __syncthreads();
  if (!*s_bail) {
    if (tid == 0) {
      int a_ = __hip_atomic_fetch_add(&bar[BAR_CNT(bid >> 3)], 1,
                                      __ATOMIC_RELEASE, __HIP_MEMORY_SCOPE_AGENT);
      if (a_ == GRPSZ - 1) {
        __hip_atomic_store(&bar[BAR_CNT(bid >> 3)], 0, __ATOMIC_RELAXED, __HIP_MEMORY_SCOPE_AGENT);
        __hip_atomic_store(&bar[BAR_FLAG(bid >> 3)], t, __ATOMIC_RELEASE, __HIP_MEMORY_SCOPE_AGENT);
      }
    }
    if (bid == ROOT) {
      if (tid < NGRP) {
        int it = 0;
        while (__hip_atomic_load(&bar[BAR_FLAG(tid)], __ATOMIC_RELAXED, __HIP_MEMORY_SCOPE_AGENT) < t) {
          __builtin_amdgcn_s_sleep(1);
          if (++it > (1 << 24)) { *s_bail = 1; break; }
        }
      }
      __syncthreads();
      if (tid == 0)
        __hip_atomic_store(&bar[BAR_GEN], t, __ATOMIC_RELEASE, __HIP_MEMORY_SCOPE_AGENT);
    } else if (tid == 0) {
      int it = 0;
      while (__hip_atomic_load(&bar[BAR_GEN], __ATOMIC_RELAXED, __HIP_MEMORY_SCOPE_AGENT) < t) {
        __builtin_amdgcn_s_sleep(1);
        if (++it > (1 << 24)) { *s_bail = 1; break; }
      }
    }
  }
  __syncthreads();
}

// full-K dot: bf16 weights (L2-cached), fp32 x from LDS. K % 32 == 0.
__device__ __forceinline__ float dotK(const float* xs, const u16* w, int K) {
  const uint4* wp = (const uint4*)w;
  const float4* xp = (const float4*)xs;
  float a0 = 0.f, a1 = 0.f, a2 = 0.f, a3 = 0.f;
  #pragma unroll 2
  for (int i = 0; i < (K >> 5); ++i) {
    uint4 w0 = wp[i*4+0], w1 = wp[i*4+1], w2 = wp[i*4+2], w3 = wp[i*4+3];
    float4 x0 = xp[i*8+0], x1 = xp[i*8+1], x2 = xp[i*8+2], x3 = xp[i*8+3];
    float4 x4 = xp[i*8+4], x5 = xp[i*8+5], x6 = xp[i*8+6], x7 = xp[i*8+7];
    a0 += blo(w0.x)*x0.x + bhi(w0.x)*x0.y + blo(w0.y)*x0.z + bhi(w0.y)*x0.w
        + blo(w0.z)*x1.x + bhi(w0.z)*x1.y + blo(w0.w)*x1.z + bhi(w0.w)*x1.w;
    a1 += blo(w1.x)*x2.x + bhi(w1.x)*x2.y + blo(w1.y)*x2.z + bhi(w1.y)*x2.w
        + blo(w1.z)*x3.x + bhi(w1.z)*x3.y + blo(w1.w)*x3.z + bhi(w1.w)*x3.w;
    a2 += blo(w2.x)*x4.x + bhi(w2.x)*x4.y + blo(w2.y)*x4.z + bhi(w2.y)*x4.w
        + blo(w2.z)*x5.x + bhi(w2.z)*x5.y + blo(w2.w)*x5.z + bhi(w2.w)*x5.w;
    a3 += blo(w3.x)*x6.x + bhi(w3.x)*x6.y + blo(w3.y)*x6.z + bhi(w3.y)*x6.w
        + blo(w3.z)*x7.x + bhi(w3.z)*x7.y + blo(w3.w)*x7.z + bhi(w3.w)*x7.w;
  }
  return (a0 + a1) + (a2 + a3);
}

// ======== J1: attn LSTM step s; rows ug*16..+16, batches bg*4..+4 ========
__device__ __forceinline__ void j1_job(const KArgs& a, float* sm, int s) {
  const int tid = threadIdx.x, bid = blockIdx.x;
  const int ug = (bid & 7)*8 + (bid >> 6), bg = (bid >> 3) & 7;
  float* ws = a.ws;
  const u16* wb = a.wb;
  const int pprev = (s + 1) & 1, pcur = s & 1;
  const float* ctxp = ws + OFF_CTX + pprev * 16384;
  const float* ahp  = ws + OFF_AHC + pprev * 32768;
  const float* Xs   = ws + OFF_X + s * 8192;
  float* xbuf = sm;                 // 4 * 1800
  float* sred = sm + 8224;          // 256
  {
    const int bq = tid >> 6, lane = tid & 63;
    const int b = bg*4 + bq;
    const float* ctxb = ctxp + b*512;
    auto ah_at = [&](int idx) -> const f32x4* {
      const int u = (idx - 192)*4;
      return (const f32x4*)(ahp + chunkW(u >> 4, bg) + bq*16 + (u & 15));
    };
    f32x4 v0,v1,v3,v4,v5,v6;
    NTLD4(v0, (const f32x4*)(ctxb + lane*4));
    NTLD4(v1, (const f32x4*)(ctxb + (lane+64)*4));
    NTLD4(v3, ah_at(lane+192)); NTLD4(v4, ah_at(lane+256));
    NTLD4(v5, ah_at(lane+320)); NTLD4(v6, ah_at(lane+384));
    f32x4 v2 = *((const f32x4*)(Xs + b*256 + lane*4));   // X immutable -> cached
    NTFENCE();
    f32x4* dst = (f32x4*)(xbuf + bq*1800);
    dst[lane] = v0; dst[lane+64] = v1; dst[lane+128] = v2; dst[lane+192] = v3;
    dst[lane+256] = v4; dst[lane+320] = v5; dst[lane+384] = v6;
  }
  __syncthreads();
  {
    const int r8 = tid >> 2, bsub = tid & 3;
    const int gate = r8 >> 4, ui = r8 & 15;
    const int rr = gate*1024 + ug*16 + ui;
    const float* xs = xbuf + bsub*1800;
    float acc = dotK(xs, wb + B_AWIH + rr*768, 768)
              + dotK(xs + 768, wb + B_AWHH + rr*1024, 1024)
              + a.abih[rr] + a.abhh[rr];
    sred[tid] = acc;
  }
  __syncthreads();
  if (tid < 64) {
    const int ui2 = tid >> 2, b2 = tid & 3;
    const float gi = sred[(ui2)*4 + b2];
    const float gf = sred[(16+ui2)*4 + b2];
    const float gg = sred[(32+ui2)*4 + b2];
    const float go = sred[(48+ui2)*4 + b2];
    float* acs = ws + OFF_ACS;
    const float c = sigf(gf)*acs[bid*64 + tid] + sigf(gi)*ftanh(gg);
    acs[bid*64 + tid] = c;
    (ws + OFF_AHC + pcur*32768)[bid*64 + b2*16 + ui2] = sigf(go)*ftanh(c);
  }
}

// ======== JG: dec-LSTM gates minus ctx part; job j ========
__device__ __forceinline__ void jg_job(const KArgs& a, float* sm, int s, int j) {
  const int tid = threadIdx.x;
  const int ug = (j & 7)*8 + (j >> 6), bg = (j >> 3) & 7;
  float* ws = a.ws;
  const u16* wb = a.wb;
  const float* dhp = ws + OFF_DHC + ((s+1)&1)*32768;   // dh(s-1)
  const float* ahp = ws + OFF_AHC + (s&1)*32768;       // ah(s)
  float* xbuf = sm;                 // 4 * 2056
  __syncthreads();
  {
    const int bq = tid >> 6, lane = tid & 63;
    auto ap = [&](int idx) -> const f32x4* {
      if (idx < 256) { const int u = idx*4;
        return (const f32x4*)(dhp + chunkW(u >> 4, bg) + bq*16 + (u & 15)); }
      const int u = (idx-256)*4;
      return (const f32x4*)(ahp + chunkW(u >> 4, bg) + bq*16 + (u & 15));
    };
    f32x4 v0,v1,v2,v3,v4,v5,v6,v7;
    NTLD4(v0, ap(lane));       NTLD4(v1, ap(lane+64));
    NTLD4(v2, ap(lane+128));   NTLD4(v3, ap(lane+192));
    NTLD4(v4, ap(lane+256));   NTLD4(v5, ap(lane+320));
    NTLD4(v6, ap(lane+384));   NTLD4(v7, ap(lane+448));
    NTFENCE();
    f32x4* dst = (f32x4*)(xbuf + bq*2056);
    dst[lane] = v0; dst[lane+64] = v1; dst[lane+128] = v2; dst[lane+192] = v3;
    dst[lane+256] = v4; dst[lane+320] = v5; dst[lane+384] = v6; dst[lane+448] = v7;
  }
  __syncthreads();
  {
    const int r8 = tid >> 2, bsub = tid & 3;
    const int gate = r8 >> 4, ui = r8 & 15;
    const int rr = gate*1024 + ug*16 + ui;
    const float* xs = xbuf + bsub*2056;
    float acc = dotK(xs, wb + B_DWHH + rr*1024, 1024)
              + dotK(xs + 1024, wb + B_DWIH + rr*1536, 1024)
              + a.dbih[rr] + a.dbhh[rr];
    (ws + OFF_GPC)[j*256 + tid] = acc;
  }
}

// ======== P3: finish dec LSTM step s; job = bid ========
__device__ __forceinline__ void p3_job(const KArgs& a, float* sm, int s) {
  const int tid = threadIdx.x, bid = blockIdx.x;
  const int ug = (bid & 7)*8 + (bid >> 6), bg = (bid >> 3) & 7;
  float* ws = a.ws;
  const u16* wb = a.wb;
  const float* ctxc = ws + OFF_CTX + (s&1)*16384;
  float* xbuf = sm;                 // 4 * 520
  float* sred = sm + 8224;
  __syncthreads();
  const int bq = tid >> 6, lane = tid & 63;
  const int b = bg*4 + bq;
  f32x4 v0, v1; float gp;
  NTLD4(v0, (const f32x4*)(ctxc + b*512 + lane*4));
  NTLD4(v1, (const f32x4*)(ctxc + b*512 + (lane+64)*4));
  NTLD1(gp, (ws + OFF_GPC + bid*256 + tid));
  NTFENCE();
  ((f32x4*)(xbuf + bq*520))[lane] = v0;
  ((f32x4*)(xbuf + bq*520))[lane+64] = v1;
  __syncthreads();
  {
    const int r8 = tid >> 2, bsub = tid & 3;
    const int gate = r8 >> 4, ui = r8 & 15;
    const int rr = gate*1024 + ug*16 + ui;
    float acc = dotK(xbuf + bsub*520, wb + B_DWIH + rr*1536 + 1024, 512) + gp;
    sred[tid] = acc;
  }
  __syncthreads();
  if (tid < 64) {
    const int ui2 = tid >> 2, b2 = tid & 3;
    const float gi = sred[(ui2)*4 + b2];
    const float gf = sred[(16+ui2)*4 + b2];
    const float gg = sred[(32+ui2)*4 + b2];
    const float go = sred[(48+ui2)*4 + b2];
    float* dcs = ws + OFF_DCS;
    const float c = sigf(gf)*dcs[bid*64 + tid] + sigf(gi)*ftanh(gg);
    dcs[bid*64 + tid] = c;
    (ws + OFF_DHC + (s&1)*32768)[bid*64 + b2*16 + ui2] = sigf(go)*ftanh(c);
  }
}

// ======== J4: static conv + log-prior (block-private, cached) ========
__device__ __forceinline__ void j4_job(const KArgs& a, float* sm) {
  const int tid = threadIdx.x, b4 = blockIdx.x;
  float* ws = a.ws;
  float* aw   = ws + OFF_AW;
  float* fbuf = ws + OFF_FBUF;
  float* pbuf = ws + OFF_PBUF;
  __syncthreads();
  if (tid < 224) sm[tid] = (tid >= 10 && tid < 210) ? aw[b4*224 + tid - 10] : 0.f;
  __syncthreads();
  if (tid < 200) {
    #pragma unroll
    for (int j = 0; j < 8; ++j) {
      float p = 0.f;
      #pragma unroll
      for (int tau = 0; tau < 21; ++tau) p += sm[tid + tau] * a.F[j*21 + tau];
      fbuf[b4*1600 + tid*8 + j] = p;
    }
    float pp = 0.f;
    #pragma unroll
    for (int tau = 0; tau < 11; ++tau) pp += sm[tid + tau] * a.prior[tau];
    pbuf[b4*224 + tid] = __logf(fmaxf(pp, 1e-6f));
  }
}

// ======== outproj for step sprev; blocks 64..223: og = bid-64, rg = og>>3, bg = og&7 ========
__device__ __forceinline__ void outproj_job(const KArgs& a, float* sm, int sprev) {
  const int tid = threadIdx.x, bid = blockIdx.x;
  const int og = bid - 64, rg = og >> 3, bg = og & 7;
  const int pdm = sprev & 1;
  float* ws = a.ws;
  const u16* wb = a.wb;
  const float* dhp  = ws + OFF_DHC + pdm*32768;
  const float* ctxp = ws + OFF_CTX + pdm*16384;
  float* xbuf = sm;                 // 4 * 1600 (8 chunks of 200 floats: 192 data + 8 pad)
  float* sred = sm + 8224;
  __syncthreads();
  {
    const int bq = tid >> 6, lane = tid & 63;
    const int b = bg*4 + bq;
    auto ap = [&](int idx) -> const f32x4* {
      if (idx < 256) { const int u = idx*4;
        return (const f32x4*)(dhp + chunkW(u >> 4, bg) + bq*16 + (u & 15)); }
      return (const f32x4*)(ctxp + b*512 + (idx-256)*4);
    };
    f32x4 v0,v1,v2,v3,v4,v5;
    NTLD4(v0, ap(lane));       NTLD4(v1, ap(lane+64));
    NTLD4(v2, ap(lane+128));   NTLD4(v3, ap(lane+192));
    NTLD4(v4, ap(lane+256));   NTLD4(v5, ap(lane+320));
    NTFENCE();
    float* base = xbuf + bq*1600;
    auto put = [&](int f, f32x4 v) {
      const int cf = f / 48, wf = f % 48;          // pad +8 floats per 192-chunk
      *(f32x4*)(base + cf*200 + wf*4) = v;         // 2-way max on ds_write (free)
    };
    put(lane, v0); put(lane+64, v1); put(lane+128, v2);
    put(lane+192, v3); put(lane+256, v4); put(lane+320, v5);
  }
  __syncthreads();
  {
    const int kc = tid & 7, r = (tid >> 3) & 7, bq = tid >> 6;
    const int rr = rg*8 + r;
    // kc*200: bank offset 8*kc%32 -> kc,kc+4 share = 2-way (free). Old kc*192
    // was 8-way (192%32==0) = the 3.4e8 SQ_LDS_BANK_CONFLICT of r5.
    float p = dotK(xbuf + bq*1600 + kc*200, wb + B_ACW + rr*1536 + kc*192, 192);
    sred[tid] = p;
  }
  __syncthreads();
  if (tid < 32) {
    const int bq2 = tid >> 3, r2 = tid & 7;
    const int rr2 = rg*8 + r2, b2 = bg*4 + bq2;
    float tot = a.acb[rr2];
    #pragma unroll
    for (int q = 0; q < 8; ++q) tot += sred[bq2*64 + r2*8 + q];
    a.out[(b2*NMELS + (rr2 >> 1))*TMELS + sprev*2 + (rr2 & 1)] = tot;
  }
}

// ======== DCA (blocks 0..31, b = bid) ========
__device__ __forceinline__ void dca_step(const KArgs& a, float* sm, int s) {
  const int tid = threadIdx.x, b = blockIdx.x;
  const u16* wb = a.wb;
  float* ws = a.ws;
  const int pc = s & 1;
  const float* ahp = ws + OFF_AHC + pc*32768;
  float* ctx  = ws + OFF_CTX + pc*16384;
  float* aw   = ws + OFF_AW;
  const float* fbuf = ws + OFF_FBUF;
  const float* pbuf = ws + OFF_PBUF;
  float* s_ah  = sm;            // 1024
  float* s_awp = sm + 1024;     // 224
  float* s_q   = sm + 1248;     // 128
  float* s_G   = sm + 1376;     // 176
  float* s_e   = sm + 1552;     // 208
  float* s_gg  = sm + 1760;     // 1600
  float* s_ff  = sm + 3360;     // 1600
  float* s_red = sm + 4960;     // 256
  float* s_awn = sm + 5216;     // 200
  f32x4 vah;
  {
    const int u = tid*4;
    NTLD4(vah, (const f32x4*)(ahp + chunkW(u >> 4, b >> 2) + (b & 3)*16 + (u & 15)));
  }
  if (tid < 224) s_awp[tid] = (tid >= 10 && tid < 210) ? aw[b*224 + tid - 10] : 0.f;
  for (int i = tid; i < 1600; i += NTHR) s_ff[i] = fbuf[b*1600 + i];
  NTFENCE();
  *(f32x4*)(s_ah + tid*4) = vah;
  __syncthreads();
  // q = tanh(Wq @ ah + bq)
  {
    const int o = tid & 127, half = tid >> 7;
    const uint4* wq = (const uint4*)(wb + B_WQ + o*1024 + half*512);
    const float* xa = s_ah + half*512;
    float p = 0.f;
    #pragma unroll 8
    for (int q8 = 0; q8 < 64; ++q8) {
      uint4 w = wq[q8];
      const float* xq = xa + q8*8;
      p += blo(w.x)*xq[0] + bhi(w.x)*xq[1] + blo(w.y)*xq[2] + bhi(w.y)*xq[3]
         + blo(w.z)*xq[4] + bhi(w.z)*xq[5] + blo(w.w)*xq[6] + bhi(w.w)*xq[7];
    }
    s_red[tid] = p;
  }
  __syncthreads();
  if (tid < 128) s_q[tid] = ftanh(s_red[tid] + s_red[128 + tid] + a.bq[tid]);
  __syncthreads();
  if (tid < 168) {
    const float4* vp = (const float4*)(a.V + tid*128);
    float p = 0.f;
    #pragma unroll
    for (int q4 = 0; q4 < 32; ++q4) {
      float4 w = vp[q4];
      const float* xq = s_q + q4*4;
      p += w.x*xq[0] + w.y*xq[1] + w.z*xq[2] + w.w*xq[3];
    }
    s_G[tid] = p;
  }
  __syncthreads();
  for (int idx = tid; idx < 1600; idx += NTHR) {
    const int pos = idx >> 3, d = idx & 7;
    float p = 0.f;
    #pragma unroll
    for (int tau = 0; tau < 21; ++tau) p += s_awp[pos + tau] * s_G[d*21 + tau];
    s_gg[idx] = p;
  }
  __syncthreads();
  #pragma unroll 1
  for (int ro = 0; ro < 4; ++ro) {
    const int pos = ro*64 + (tid >> 2), sub = tid & 3;
    float av = 0.f;
    if (pos < 200) {
      const float* fpos = s_ff + pos*8;
      const float* gpos = s_gg + pos*8;
      #pragma unroll 4
      for (int fi = 0; fi < 32; ++fi) {
        const int ff = sub*32 + fi;
        const float4* Up = (const float4*)(a.U + ff*8);
        const float4* Tp = (const float4*)(a.T + ff*8);
        float4 u0 = Up[0], u1 = Up[1], t0 = Tp[0], t1 = Tp[1];
        float h = a.Tb[ff];
        h += u0.x*fpos[0] + u0.y*fpos[1] + u0.z*fpos[2] + u0.w*fpos[3]
           + u1.x*fpos[4] + u1.y*fpos[5] + u1.z*fpos[6] + u1.w*fpos[7];
        h += t0.x*gpos[0] + t0.y*gpos[1] + t0.z*gpos[2] + t0.w*gpos[3]
           + t1.x*gpos[4] + t1.y*gpos[5] + t1.z*gpos[6] + t1.w*gpos[7];
        av += a.vv[ff] * ftanh(h);
      }
    }
    av += __shfl_xor(av, 1);
    av += __shfl_xor(av, 2);
    if (sub == 0 && pos < 200) s_e[pos] = av + pbuf[b*224 + pos];
  }
  __syncthreads();
  float mval = (tid < 200) ? s_e[tid] : -1e30f;
  #pragma unroll
  for (int off = 32; off > 0; off >>= 1) mval = fmaxf(mval, __shfl_xor(mval, off));
  if ((tid & 63) == 0) s_red[tid >> 6] = mval;
  __syncthreads();
  const float m = fmaxf(fmaxf(s_red[0], s_red[1]), fmaxf(s_red[2], s_red[3]));
  const float ex = (tid < 200) ? __expf(s_e[tid] - m) : 0.f;
  float sv = ex;
  #pragma unroll
  for (int off = 32; off > 0; off >>= 1) sv += __shfl_xor(sv, off);
  if ((tid & 63) == 0) s_red[4 + (tid >> 6)] = sv;
  __syncthreads();
  const float inv = frcp(s_red[4] + s_red[5] + s_red[6] + s_red[7]);
  if (tid < 200) {
    const float awv = ex * inv;
    aw[b*224 + tid] = awv;
    s_awn[tid] = awv;
    a.out[2048000 + b*80000 + tid*400 + s] = awv;
  }
  __syncthreads();
  #pragma unroll 1
  for (int d = tid; d < 512; d += NTHR) {
    const uint4* mp = (const uint4*)(wb + B_MEMT + b*102400 + d*200);
    float p = 0.f;
    #pragma unroll 5
    for (int q = 0; q < 25; ++q) {
      uint4 v = mp[q];
      const float* aa = s_awn + q*8;
      p += blo(v.x)*aa[0] + bhi(v.x)*aa[1] + blo(v.y)*aa[2] + bhi(v.y)*aa[3]
         + blo(v.z)*aa[4] + bhi(v.z)*aa[5] + blo(v.w)*aa[6] + bhi(v.w)*aa[7];
    }
    ctx[b*512 + d] = p;
  }
}

// ======== init: zero state + one-hot aw + barrier region ========
__global__ __launch_bounds__(NTHR) void init_kernel(KArgs a) {
  const int gtid = blockIdx.x*NTHR + threadIdx.x;
  const int str = gridDim.x*NTHR;
  float* ws = a.ws;
  for (int i = gtid; i < 8192; i += str) a.bar[i] = 0;
  for (int i = gtid; i < ZERO_CNT; i += str) ws[i] = 0.f;
  float* aw = ws + OFF_AW;
  for (int i = gtid; i < 32*224; i += str) aw[i] = ((i % 224) == 0) ? 1.f : 0.f;
}

// ======== convert weights to bf16 (+ memory transpose) ========
__global__ __launch_bounds__(NTHR) void conv_kernel(KArgs a) {
  const int gtid = blockIdx.x*NTHR + threadIdx.x;
  const int str = gridDim.x*NTHR;
  u16* wb = a.wb;
  for (int i = gtid; i < 3145728; i += str) wb[B_AWIH + i] = f2b(a.aWih[i]);
  for (int i = gtid; i < 4194304; i += str) wb[B_AWHH + i] = f2b(a.aWhh[i]);
  for (int i = gtid; i < 6291456; i += str) wb[B_DWIH + i] = f2b(a.dWih[i]);
  for (int i = gtid; i < 4194304; i += str) wb[B_DWHH + i] = f2b(a.dWhh[i]);
  for (int i = gtid; i < 245760;  i += str) wb[B_ACW  + i] = f2b(a.acW[i]);
  for (int i = gtid; i < 131072;  i += str) wb[B_WQ   + i] = f2b(a.Wq[i]);
  for (int i = gtid; i < 3276800; i += str) {
    const int b = i / 102400, rem = i - b*102400;
    const int d = rem / 200, t = rem - d*200;
    wb[B_MEMT + i] = f2b(a.memory[b*102400 + t*512 + d]);
  }
}

// ======== prenet for all (s,b) pairs; grid 12800 ========
__global__ __launch_bounds__(NTHR) void prenet_kernel(KArgs a) {
  __shared__ float sm[384];
  const int tid = threadIdx.x;
  const int pair = blockIdx.x;           // s*32 + b
  const int s = pair >> 5, b = pair & 31;
  float* X = a.ws + OFF_X;
  if (tid < 80) {
    float v = 0.f;
    if (s > 0) v = a.mels[(b*NMELS + tid)*TMELS + 2*s - 1];
    sm[tid] = v;
  }
  __syncthreads();
  float a1 = a.pb1[tid];
  #pragma unroll 4
  for (int k = 0; k < 80; ++k) a1 += a.pW1[tid*80 + k] * sm[k];
  a1 = fmaxf(a1, 0.f);
  __syncthreads();
  sm[128 + tid] = a1;
  __syncthreads();
  float a2 = a.pb2[tid];
  #pragma unroll 4
  for (int k = 0; k < 256; ++k) a2 += a.pW2[tid*256 + k] * sm[128 + k];
  a2 = fmaxf(a2, 0.f);
  X[(s*BATCH + b)*256 + tid] = a2;
}

// ======== persistent loop: 2 barriers/step ========
// alpha(s): DCA(s) [0..31] | JG(s) [32..511; 32..63 doubled] | outproj(s-1) [64..223]
// beta(s):  J1(s+1) + P3(s) [all] | J4(s+1) [0..31]
__global__ __launch_bounds__(NTHR, 2) void loop_kernel(KArgs a) {
  __shared__ float sm[8480];
  __shared__ int s_bail;
  const int tid = threadIdx.x;
  const int bid = blockIdx.x;
  int* bar = a.bar;
  int gen = 0;
  if (tid == 0) s_bail = 0;
  __syncthreads();

  // prologue: J1(0) on all blocks; J4(step 0) on 0..31
  j1_job(a, sm, 0);
  if (bid < 32) j4_job(a, sm);
  gbar(bar, &s_bail, gen);

  for (int s = 0; s < NSTEP; ++s) {
    // ---- alpha ----
    if (bid < 32) {
      dca_step(a, sm, s);
    } else {
      jg_job(a, sm, s, bid - 32);
      if (bid < 64) jg_job(a, sm, s, bid + 448);
      if (bid >= 64 && bid < 224 && s > 0) outproj_job(a, sm, s - 1);
    }
    gbar(bar, &s_bail, gen);
    // ---- beta ----
    if (s + 1 < NSTEP) j1_job(a, sm, s + 1);
    p3_job(a, sm, s);
    if (bid < 32 && s + 1 < NSTEP) j4_job(a, sm);
    gbar(bar, &s_bail, gen);
  }

  // epilogue: final output projection
  if (bid >= 64 && bid < 224) outproj_job(a, sm, NSTEP - 1);
}

extern "C" void kernel_launch(void* const* d_in, const int* in_sizes, int n_in,
                              void* d_out, int out_size, void* d_ws, size_t ws_size,
                              hipStream_t stream) {
  (void)in_sizes; (void)n_in; (void)out_size; (void)ws_size;
  KArgs a;
  a.mels   = (const float*)d_in[0];
  a.memory = (const float*)d_in[1];
  a.pW1 = (const float*)d_in[2];  a.pb1 = (const float*)d_in[3];
  a.pW2 = (const float*)d_in[4];  a.pb2 = (const float*)d_in[5];
  a.aWih = (const float*)d_in[6]; a.aWhh = (const float*)d_in[7];
  a.abih = (const float*)d_in[8]; a.abhh = (const float*)d_in[9];
  a.Wq = (const float*)d_in[10];  a.bq = (const float*)d_in[11];
  a.V  = (const float*)d_in[12];  a.F  = (const float*)d_in[13];
  a.U  = (const float*)d_in[14];  a.T  = (const float*)d_in[15];
  a.Tb = (const float*)d_in[16];  a.vv = (const float*)d_in[17];
  a.prior = (const float*)d_in[18];
  a.dWih = (const float*)d_in[19]; a.dWhh = (const float*)d_in[20];
  a.dbih = (const float*)d_in[21]; a.dbhh = (const float*)d_in[22];
  a.acW  = (const float*)d_in[23]; a.acb  = (const float*)d_in[24];
  a.out = (float*)d_out;
  a.bar = (int*)d_ws;
  a.ws  = (float*)((char*)d_ws + 32768);
  a.wb  = (u16*)(a.ws + FLOAT_END);

  hipLaunchKernelGGL(init_kernel, dim3(512), dim3(NTHR), 0, stream, a);
  hipLaunchKernelGGL(conv_kernel, dim3(2048), dim3(NTHR), 0, stream, a);
  hipLaunchKernelGGL(prenet_kernel, dim3(NSTEP*BATCH), dim3(NTHR), 0, stream, a);
  hipLaunchKernelGGL(loop_kernel, dim3(NBLK), dim3(NTHR), 0, stream, a);
}